// Round 1
// baseline (5552.386 us; speedup 1.0000x reference)
//
#include <hip/hip_runtime.h>
#include <hip/hip_bf16.h>
#include <math.h>

using bf16 = __hip_bfloat16;
typedef __attribute__((ext_vector_type(8))) short s16x8;
typedef __attribute__((ext_vector_type(4))) float f32x4;
typedef __attribute__((ext_vector_type(8))) int i32x8;
typedef __attribute__((ext_vector_type(4))) int i32x4;

#define NEG_INF_F (-1e30f)

// ---------- constants for this problem ----------
static constexpr int BATCH = 16;
static constexpr int LC = 2048;
static constexpr int LQ = 512;
static constexpr int DIM = 512;
static constexpr int FEAT = 2048;          // 4*DIM
static constexpr int MC = BATCH * LC;      // 32768
static constexpr int MQ = BATCH * LQ;      // 8192

__device__ __forceinline__ float bfs2f(short s) {
    union { float f; unsigned u; } x;
    x.u = ((unsigned)(unsigned short)s) << 16;
    return x.f;
}
__device__ __forceinline__ short f2bfs(float f) {
    bf16 h = __float2bfloat16(f);
    short s; __builtin_memcpy(&s, &h, 2);
    return s;
}
// OCP e4m3 byte -> float (decoder, epilogue only)
__device__ __forceinline__ float fp8_to_f(unsigned b) {
    const unsigned s = b >> 7, e = (b >> 3) & 15, m = b & 7;
    const int ee = e ? (int)e : 1;
    const int mm = e ? (int)(8 + m) : (int)m;
    union { unsigned u; float f; } sc; sc.u = (unsigned)(ee + 117) << 23; // 2^(ee-10)
    const float v = (float)mm * sc.f;
    return s ? -v : v;
}
// pack 8 floats -> 8 fp8 e4m3 bytes (saturating RNE via HW cvt)
__device__ __forceinline__ uint2 pk8fp8(float a0, float a1, float a2, float a3,
                                        float a4, float a5, float a6, float a7) {
    uint2 r;
    int w0 = __builtin_amdgcn_cvt_pk_fp8_f32(a0, a1, 0, false);
    w0 = __builtin_amdgcn_cvt_pk_fp8_f32(a2, a3, w0, true);
    int w1 = __builtin_amdgcn_cvt_pk_fp8_f32(a4, a5, 0, false);
    w1 = __builtin_amdgcn_cvt_pk_fp8_f32(a6, a7, w1, true);
    r.x = (unsigned)w0; r.y = (unsigned)w1;
    return r;
}

#define GLL(gp, lp) __builtin_amdgcn_global_load_lds( \
    (const __attribute__((address_space(1))) void*)(gp), \
    (__attribute__((address_space(3))) void*)(lp), 16, 0, 0)

// ---------- fp32 -> bf16 convert ----------
__global__ __launch_bounds__(256) void cvt_f32_bf16(const float* __restrict__ in,
                                                    bf16* __restrict__ out, int n) {
    int i = (blockIdx.x * 256 + threadIdx.x) * 4;
    if (i + 3 < n) {
        float4 v = *(const float4*)(in + i);
        ushort4 o;
        o.x = (unsigned short)f2bfs(v.x);
        o.y = (unsigned short)f2bfs(v.y);
        o.z = (unsigned short)f2bfs(v.z);
        o.w = (unsigned short)f2bfs(v.w);
        *(ushort4*)(out + i) = o;
    } else {
        for (int k = i; k < n; k++) out[k] = __float2bfloat16(in[k]);
    }
}

// ---------- fp32 -> fp8 e4m3 with x32 pre-scale (weights; MX scale 2^-5 compensates) ----------
__global__ __launch_bounds__(256) void cvt_f32_fp8_w(const float* __restrict__ in,
                                                     unsigned char* __restrict__ out, int n) {
    int i = (blockIdx.x * 256 + threadIdx.x) * 4;
    if (i >= n) return;
    float4 v = *(const float4*)(in + i);
    int w0 = __builtin_amdgcn_cvt_pk_fp8_f32(v.x * 32.f, v.y * 32.f, 0, false);
    w0 = __builtin_amdgcn_cvt_pk_fp8_f32(v.z * 32.f, v.w * 32.f, w0, true);
    *(int*)(out + i) = w0;
}

// ---------- per-batch transpose: Q (B,LQ,DIM) f32 -> Qt (B,DIM,LQ) bf16 ----------
__global__ __launch_bounds__(256) void transpose_q(const float* __restrict__ Q,
                                                   bf16* __restrict__ Qt) {
    __shared__ float t[32][33];
    const int b = blockIdx.z;
    const int q0 = blockIdx.x * 32, d0 = blockIdx.y * 32;
    const int tx = threadIdx.x, ty = threadIdx.y; // 32 x 8
    const float* Qb = Q + (long)b * LQ * DIM;
    bf16* Qtb = Qt + (long)b * DIM * LQ;
#pragma unroll
    for (int i = 0; i < 32; i += 8)
        t[ty + i][tx] = Qb[(long)(q0 + ty + i) * DIM + d0 + tx];
    __syncthreads();
#pragma unroll
    for (int i = 0; i < 32; i += 8)
        Qtb[(long)(d0 + ty + i) * LQ + q0 + tx] = __float2bfloat16(t[tx][ty + i]);
}

// ---------- generic bf16 MFMA GEMM: Out[M,N] = A[M,K] @ B[N,K]^T ----------
enum { MODE_PLAIN = 0, MODE_BIAS_LRELU = 1 };

template <int MODE>
__global__ __launch_bounds__(256)
void gemm_bt(const bf16* __restrict__ A, const bf16* __restrict__ B,
             void* __restrict__ Out,
             const float* __restrict__ bias,
             int N, int K,
             long strideA, long strideB, long strideO) {
    constexpr int BM = 128, BN = 128, BK = 32;
    __shared__ __align__(16) bf16 As[BM * BK];
    __shared__ __align__(16) bf16 Bs[BN * BK];

    const int z = blockIdx.z;
    const bf16* Ab = A + (long)z * strideA;
    const bf16* Bb = B + (long)z * strideB;

    const int tid = threadIdx.x;
    const int wave = tid >> 6, lane = tid & 63;
    const int wm = (wave >> 1) * 64, wn = (wave & 1) * 64;
    const int lrow = lane & 15, lq = lane >> 4;

    const int bm0 = blockIdx.y * BM;
    const int bn0 = blockIdx.x * BN;

    const int srow = tid >> 2;
    const int scol = (tid & 3) * 8;

    const bf16* ag = Ab + (long)(bm0 + srow) * K + scol;
    const bf16* bg = Bb + (long)(bn0 + srow) * K + scol;
    bf16* asl = &As[srow * BK + scol];   // byte offset = tid*16: contiguous in lane order
    bf16* bsl = &Bs[srow * BK + scol];
    const long skip64 = (long)64 * K;

    f32x4 acc[4][4];
#pragma unroll
    for (int i = 0; i < 4; i++)
#pragma unroll
        for (int j = 0; j < 4; j++) acc[i][j] = (f32x4){0.f, 0.f, 0.f, 0.f};

    for (int k0 = 0; k0 < K; k0 += BK) {
        GLL(ag, asl);
        GLL(ag + skip64, asl + 64 * BK);
        GLL(bg, bsl);
        GLL(bg + skip64, bsl + 64 * BK);
        ag += BK; bg += BK;
        __syncthreads();

        s16x8 af[4], bfv[4];
#pragma unroll
        for (int f = 0; f < 4; f++)
            af[f] = *(const s16x8*)&As[(wm + f * 16 + lrow) * BK + lq * 8];
#pragma unroll
        for (int f = 0; f < 4; f++)
            bfv[f] = *(const s16x8*)&Bs[(wn + f * 16 + lrow) * BK + lq * 8];

#pragma unroll
        for (int i = 0; i < 4; i++)
#pragma unroll
            for (int j = 0; j < 4; j++)
                acc[i][j] = __builtin_amdgcn_mfma_f32_16x16x32_bf16(af[i], bfv[j], acc[i][j], 0, 0, 0);
        __syncthreads();
    }

    // epilogue: C/D layout col=lane&15, row=(lane>>4)*4+reg  [m89/m91-verified]
#pragma unroll
    for (int i = 0; i < 4; i++) {
#pragma unroll
        for (int j = 0; j < 4; j++) {
            const int n = bn0 + wn + j * 16 + lrow;
            const float bn_bias = (MODE == MODE_PLAIN) ? 0.f : bias[n];
#pragma unroll
            for (int r = 0; r < 4; r++) {
                const int m = bm0 + wm + i * 16 + lq * 4 + r;
                const long off = (long)z * strideO + (long)m * N + n;
                float v = acc[i][j][r];
                if (MODE == MODE_PLAIN) {
                    ((bf16*)Out)[off] = __float2bfloat16(v);
                } else { // MODE_BIAS_LRELU
                    v += bn_bias;
                    v = v > 0.f ? v : 0.01f * v;
                    ((bf16*)Out)[off] = __float2bfloat16(v);
                }
            }
        }
    }
}

// ---------- fused dual GEMM, MX-fp8 K=128, pipelined ----------
// fuse = tanh(cat@Wf^T+bf), gate = sigm(cat@Wg^T+bg),
// out = Cmask ? g*fuse+(1-g)*cat : -1e30
// A = cat fp8 (scale 2^0, byte 127); B = weights pre-scaled x32 fp8 (MX scale 2^-5, byte 122).
//
// Structure (T2+T3+T5 per the catalog): 256x128 tile, 512 threads (8 waves, 4Mx2N,
// each wave owns 64x64 x {f,g}), LDS double-buffered 2x(A 32K | Bf 16K | Bg 16K)=128KiB.
// Per K-tile (128 B): 4 phases (one B-column quadrant each, 8 scaled MFMAs), raw
// s_barrier pairs around each MFMA cluster (loads stay in flight across them),
// s_setprio(1) around MFMA. All 8 GLL rounds for tile t+1 issue in phase 0 of tile t;
// the only vmcnt drain is the tile-boundary __syncthreads (~1900 cy after issue).
// LDS tiles: 16B chunks XOR-swizzled: chunk c of row m at pos c^(m&7) — keeps
// global_load_lds lane-contiguous AND makes fragment ds_reads 2-way-only = free.
__global__ __launch_bounds__(512, 2)
void gemm_dual_fp8(const unsigned char* __restrict__ A8,
                   const unsigned char* __restrict__ Bf8,
                   const unsigned char* __restrict__ Bg8,
                   float* __restrict__ Out,
                   const float* __restrict__ biasf, const float* __restrict__ biasg,
                   const unsigned char* __restrict__ cat8,
                   const int* __restrict__ cmask) {
    constexpr int BM = 256, BN = 128;
    constexpr int N = FEAT, K = FEAT;   // K in bytes per row (fp8)
    constexpr int BUF = 65536;          // A 32K | Bf 16K | Bg 16K
    __shared__ __align__(16) char lds[2 * BUF];

    const int tid = threadIdx.x;
    const int wave = tid >> 6, lane = tid & 63;
    const int wm = (wave >> 1) * 64;    // 0,64,128,192
    const int wn = (wave & 1) * 64;     // 0,64
    const int lrow = lane & 15, lq = lane >> 4;

    const int bm0 = blockIdx.y * BM;
    const int bn0 = blockIdx.x * BN;

    // ---- staging: thread t writes LDS chunk at byte tid*16 of an 8KB round (64 rows);
    // that chunk holds global row r0(+64r), k-bytes (p ^ (r0&7))*16 .. +16 ----
    const int p = tid & 7, r0 = tid >> 3;        // r0: 0..63
    const int xo = (p ^ (r0 & 7)) * 16;
    const long Kl = K;
    const unsigned char* agp = A8 + (long)(bm0 + r0) * Kl + xo;
    const unsigned char* bfgp = Bf8 + (long)(bn0 + r0) * Kl + xo;
    const unsigned char* bggp = Bg8 + (long)(bn0 + r0) * Kl + xo;

#define STAGE8(bufp, koff) do {                                  \
        char* _ab = (bufp);                                      \
        GLL(agp + (koff), _ab + tid * 16);                       \
        GLL(agp + (koff) + 64 * Kl, _ab + 8192 + tid * 16);      \
        GLL(agp + (koff) + 128 * Kl, _ab + 16384 + tid * 16);    \
        GLL(agp + (koff) + 192 * Kl, _ab + 24576 + tid * 16);    \
        GLL(bfgp + (koff), _ab + 32768 + tid * 16);              \
        GLL(bfgp + (koff) + 64 * Kl, _ab + 40960 + tid * 16);    \
        GLL(bggp + (koff), _ab + 49152 + tid * 16);              \
        GLL(bggp + (koff) + 64 * Kl, _ab + 57344 + tid * 16);    \
    } while (0)

    // ---- fragment ds_read offsets (loop-invariant): frag (row, kq=lq) half h
    // stored at row*128 + ((lq*2+h)^(row&7))*16; note off(h=1) = off(h=0) ^ 16 ----
    int offA[4], offB[4];
#pragma unroll
    for (int f = 0; f < 4; f++) {
        const int ra = wm + f * 16 + lrow;       // 0..255
        offA[f] = ra * 128 + (((lq * 2) ^ (ra & 7)) * 16);
        const int rb = wn + f * 16 + lrow;       // 0..127
        offB[f] = rb * 128 + (((lq * 2) ^ (rb & 7)) * 16);
    }

    f32x4 accf[4][4], accg[4][4];
#pragma unroll
    for (int i = 0; i < 4; i++)
#pragma unroll
        for (int j = 0; j < 4; j++) {
            accf[i][j] = (f32x4){0.f, 0.f, 0.f, 0.f};
            accg[i][j] = (f32x4){0.f, 0.f, 0.f, 0.f};
        }

    // prologue: stage tile 0 into buf 0
    STAGE8(lds, 0);
    __syncthreads();   // drains vmcnt(0): tile 0 resident

    constexpr int NT = K / 128;   // 16 K-tiles
    for (int kt = 0; kt < NT; ++kt) {
        char* cb = lds + (kt & 1) * BUF;          // compute buffer
        char* nb = lds + ((kt & 1) ^ 1) * BUF;    // stage target
        const char* Asb = cb;
        const char* Bfb = cb + 32768;
        const char* Bgb = cb + 49152;

        // phase 0 front: A fragments for all 4 row-quadrants + issue next-tile stage
        i32x8 af[4];
#pragma unroll
        for (int f = 0; f < 4; f++) {
            const i32x4 lo = *(const i32x4*)(Asb + offA[f]);
            const i32x4 hi = *(const i32x4*)(Asb + (offA[f] ^ 16));
            af[f][0] = lo[0]; af[f][1] = lo[1]; af[f][2] = lo[2]; af[f][3] = lo[3];
            af[f][4] = hi[0]; af[f][5] = hi[1]; af[f][6] = hi[2]; af[f][7] = hi[3];
        }
        if (kt + 1 < NT) STAGE8(nb, (long)(kt + 1) * 128);

#pragma unroll
        for (int j = 0; j < 4; j++) {
            i32x8 bfj, bgj;
            {
                const i32x4 lo = *(const i32x4*)(Bfb + offB[j]);
                const i32x4 hi = *(const i32x4*)(Bfb + (offB[j] ^ 16));
                bfj[0] = lo[0]; bfj[1] = lo[1]; bfj[2] = lo[2]; bfj[3] = lo[3];
                bfj[4] = hi[0]; bfj[5] = hi[1]; bfj[6] = hi[2]; bfj[7] = hi[3];
            }
            {
                const i32x4 lo = *(const i32x4*)(Bgb + offB[j]);
                const i32x4 hi = *(const i32x4*)(Bgb + (offB[j] ^ 16));
                bgj[0] = lo[0]; bgj[1] = lo[1]; bgj[2] = lo[2]; bgj[3] = lo[3];
                bgj[4] = hi[0]; bgj[5] = hi[1]; bgj[6] = hi[2]; bgj[7] = hi[3];
            }
            // phase lockstep: all waves enter the MFMA cluster together.
            // raw s_barrier: no counter drain -> staging loads stay in flight.
            __builtin_amdgcn_s_barrier();
            __builtin_amdgcn_s_setprio(1);
#pragma unroll
            for (int i = 0; i < 4; i++)
                accf[i][j] = __builtin_amdgcn_mfma_scale_f32_16x16x128_f8f6f4(
                    af[i], bfj, accf[i][j], 0, 0, 0, 127, 0, 122);
#pragma unroll
            for (int i = 0; i < 4; i++)
                accg[i][j] = __builtin_amdgcn_mfma_scale_f32_16x16x128_f8f6f4(
                    af[i], bgj, accg[i][j], 0, 0, 0, 127, 0, 122);
            __builtin_amdgcn_s_setprio(0);
            if (j < 3) __builtin_amdgcn_s_barrier();
        }
        // tile boundary: drain vmcnt (next tile staged) + full barrier/fence
        __syncthreads();
    }
#undef STAGE8

    // epilogue: C/D layout col=lane&15, row=(lane>>4)*4+reg (shape-determined)
#pragma unroll
    for (int j = 0; j < 4; j++) {
        const int n = bn0 + wn + j * 16 + lrow;
        const float bfb = biasf[n];
        const float bgb = biasg[n];
#pragma unroll
        for (int i = 0; i < 4; i++) {
#pragma unroll
            for (int r = 0; r < 4; r++) {
                const int m = bm0 + wm + i * 16 + lq * 4 + r;
                const long off = (long)m * N + n;
                const float vf = accf[i][j][r] + bfb;
                const float vg = accg[i][j][r] + bgb;
                const float e = __expf(2.0f * fabsf(vf));
                const float th = copysignf(1.0f - 2.0f / (e + 1.0f), vf);
                const float g = 1.0f / (1.0f + __expf(-vg));
                const float c = fp8_to_f(cat8[off]);
                Out[off] = cmask[m] ? (g * th + (1.0f - g) * c) : NEG_INF_F;
            }
        }
    }
}

// ---------- masked row softmax over LQ=512, in place on bf16 S ----------
__global__ __launch_bounds__(256) void softmax_rows(bf16* __restrict__ S,
                                                    const int* __restrict__ Cmask,
                                                    const int* __restrict__ Qmask) {
    const int row = blockIdx.x;         // 0 .. B*LC-1
    const int b = row >> 11;            // LC = 2048
    const int tid = threadIdx.x;
    bf16* srow = S + (long)row * LQ;
    const int* qm = Qmask + b * LQ;
    __shared__ float red[8];

    if (Cmask[row] == 0) {
        const bf16 u = __float2bfloat16(1.0f / 512.0f);
        srow[tid] = u;
        srow[tid + 256] = u;
        return;
    }
    const int q0 = qm[tid], q1 = qm[tid + 256];
    float v0 = q0 ? __bfloat162float(srow[tid]) : -3e38f;
    float v1 = q1 ? __bfloat162float(srow[tid + 256]) : -3e38f;
    float mx = fmaxf(v0, v1);
#pragma unroll
    for (int o = 32; o > 0; o >>= 1) mx = fmaxf(mx, __shfl_down(mx, o, 64));
    const int wave = tid >> 6, lane = tid & 63;
    if (lane == 0) red[wave] = mx;
    __syncthreads();
    const float m4 = fmaxf(fmaxf(red[0], red[1]), fmaxf(red[2], red[3]));
    float e0 = q0 ? __expf(v0 - m4) : 0.f;
    float e1 = q1 ? __expf(v1 - m4) : 0.f;
    float s = e0 + e1;
#pragma unroll
    for (int o = 32; o > 0; o >>= 1) s += __shfl_down(s, o, 64);
    if (lane == 0) red[4 + wave] = s;
    __syncthreads();
    const float tot = red[4] + red[5] + red[6] + red[7];
    if (!(tot > 0.f)) {
        const bf16 u = __float2bfloat16(1.0f / 512.0f);
        srow[tid] = u;
        srow[tid + 256] = u;
        return;
    }
    const float inv = 1.0f / tot;
    srow[tid] = __float2bfloat16(e0 * inv);
    srow[tid + 256] = __float2bfloat16(e1 * inv);
}

// ---------- build cat = [C | attn | attn-C | attn*C] as fp8 e4m3 ----------
__global__ __launch_bounds__(256) void build_cat(const bf16* __restrict__ Cb,
                                                 const bf16* __restrict__ attn,
                                                 unsigned char* __restrict__ cat8) {
    const long t = (long)blockIdx.x * 256 + threadIdx.x;
    const int m = (int)(t >> 6);
    const int c = (int)(t & 63) << 3;
    const s16x8 cv = *(const s16x8*)((const short*)Cb + (long)m * DIM + c);
    const s16x8 av = *(const s16x8*)((const short*)attn + (long)m * DIM + c);
    float cf[8], af_[8];
#pragma unroll
    for (int i = 0; i < 8; i++) { cf[i] = bfs2f(cv[i]); af_[i] = bfs2f(av[i]); }
    unsigned char* rowp = cat8 + (long)m * FEAT + c;
    *(uint2*)(rowp) = pk8fp8(cf[0], cf[1], cf[2], cf[3], cf[4], cf[5], cf[6], cf[7]);
    *(uint2*)(rowp + 512) = pk8fp8(af_[0], af_[1], af_[2], af_[3], af_[4], af_[5], af_[6], af_[7]);
    *(uint2*)(rowp + 1024) = pk8fp8(af_[0] - cf[0], af_[1] - cf[1], af_[2] - cf[2], af_[3] - cf[3],
                                    af_[4] - cf[4], af_[5] - cf[5], af_[6] - cf[6], af_[7] - cf[7]);
    *(uint2*)(rowp + 1536) = pk8fp8(af_[0] * cf[0], af_[1] * cf[1], af_[2] * cf[2], af_[3] * cf[3],
                                    af_[4] * cf[4], af_[5] * cf[5], af_[6] * cf[6], af_[7] * cf[7]);
}

extern "C" void kernel_launch(void* const* d_in, const int* in_sizes, int n_in,
                              void* d_out, int out_size, void* d_ws, size_t ws_size,
                              hipStream_t stream) {
    (void)in_sizes; (void)n_in; (void)out_size; (void)ws_size;
    const float* C = (const float*)d_in[0];
    const float* Q = (const float*)d_in[1];
    const int* Cmask = (const int*)d_in[2];
    const int* Qmask = (const int*)d_in[3];
    const float* W1 = (const float*)d_in[4];
    const float* b1 = (const float*)d_in[5];
    const float* Wf = (const float*)d_in[6];
    const float* bfp = (const float*)d_in[7];
    const float* Wg = (const float*)d_in[8];
    const float* bgp = (const float*)d_in[9];
    float* out = (float*)d_out;

    // ---- workspace layout (bytes). cat8 overlaps the dead early temps
    // (W1b/Qb/Qt/C_/Q_/S are all last read before build_cat writes cat8). ----
    char* ws = (char*)d_ws;
    unsigned char* cat8 = (unsigned char*)(ws + 0);     //  67,108,864
    bf16* W1b  = (bf16*)(ws + 0);                       //     524,288
    bf16* Qb   = (bf16*)(ws + 524288);                  //   8,388,608
    bf16* Qt   = (bf16*)(ws + 8912896);                 //   8,388,608
    bf16* C_   = (bf16*)(ws + 17301504);                //  33,554,432
    bf16* Q_   = (bf16*)(ws + 50855936);                //   8,388,608
    bf16* S    = (bf16*)(ws + 59244544);                //  33,554,432 (dead before cat8 write)
    bf16* Cb   = (bf16*)(ws + 134217728);               //  33,554,432
    bf16* attn = (bf16*)(ws + 167772160);               //  33,554,432
    unsigned char* Wf8 = (unsigned char*)(ws + 201326592); // 4,194,304
    unsigned char* Wg8 = (unsigned char*)(ws + 205520896); // 4,194,304 (end ~209.7MB)

    // 1. dtype conversions
    cvt_f32_bf16<<<256, 256, 0, stream>>>(W1, W1b, DIM * DIM);
    cvt_f32_fp8_w<<<4096, 256, 0, stream>>>(Wf, Wf8, FEAT * FEAT);
    cvt_f32_fp8_w<<<4096, 256, 0, stream>>>(Wg, Wg8, FEAT * FEAT);
    cvt_f32_bf16<<<16384, 256, 0, stream>>>(C, Cb, MC * DIM);
    cvt_f32_bf16<<<4096, 256, 0, stream>>>(Q, Qb, MQ * DIM);
    transpose_q<<<dim3(16, 16, 16), dim3(32, 8), 0, stream>>>(Q, Qt);

    // 2. C_ = lrelu(C @ W1^T + b1), Q_ = lrelu(Q @ W1^T + b1)  (bf16 out)
    gemm_bt<MODE_BIAS_LRELU><<<dim3(4, 256, 1), 256, 0, stream>>>(
        Cb, W1b, C_, b1, DIM, DIM, 0, 0, 0);
    gemm_bt<MODE_BIAS_LRELU><<<dim3(4, 64, 1), 256, 0, stream>>>(
        Qb, W1b, Q_, b1, DIM, DIM, 0, 0, 0);

    // 3. S[b] = C_[b] @ Q_[b]^T  (batched, bf16 logits)
    gemm_bt<MODE_PLAIN><<<dim3(4, 16, 16), 256, 0, stream>>>(
        C_, Q_, S, nullptr, LQ, DIM,
        (long)LC * DIM, (long)LQ * DIM, (long)LC * LQ);

    // 4. masked softmax over q (in place)
    softmax_rows<<<MC, 256, 0, stream>>>(S, Cmask, Qmask);

    // 5. attn[b] = S[b] @ Q[b]   (B-operand = Qt, batched)
    gemm_bt<MODE_PLAIN><<<dim3(4, 16, 16), 256, 0, stream>>>(
        S, Qt, attn, nullptr, DIM, LQ,
        (long)LC * LQ, (long)DIM * LQ, (long)LC * DIM);

    // 6. cat8 = [C | attn | attn-C | attn*C] (fp8)
    build_cat<<<8192, 256, 0, stream>>>(Cb, attn, cat8);

    // 7+8 fused MX-fp8 dual GEMM + activations + gate blend + Cmask (fp32 out)
    gemm_dual_fp8<<<dim3(16, 128, 1), 512, 0, stream>>>(
        cat8, Wf8, Wg8, out, bfp, bgp, cat8, Cmask);
}

// Round 2
// 4195.699 us; speedup vs baseline: 1.3234x; 1.3234x over previous
//
#include <hip/hip_runtime.h>
#include <hip/hip_bf16.h>
#include <math.h>

using bf16 = __hip_bfloat16;
typedef __attribute__((ext_vector_type(8))) short s16x8;
typedef __attribute__((ext_vector_type(4))) float f32x4;
typedef __attribute__((ext_vector_type(8))) int i32x8;
typedef __attribute__((ext_vector_type(4))) int i32x4;

#define NEG_INF_F (-1e30f)

// ---------- constants for this problem ----------
static constexpr int BATCH = 16;
static constexpr int LC = 2048;
static constexpr int LQ = 512;
static constexpr int DIM = 512;
static constexpr int FEAT = 2048;          // 4*DIM
static constexpr int MC = BATCH * LC;      // 32768
static constexpr int MQ = BATCH * LQ;      // 8192

__device__ __forceinline__ float bfs2f(short s) {
    union { float f; unsigned u; } x;
    x.u = ((unsigned)(unsigned short)s) << 16;
    return x.f;
}
__device__ __forceinline__ short f2bfs(float f) {
    bf16 h = __float2bfloat16(f);
    short s; __builtin_memcpy(&s, &h, 2);
    return s;
}
// OCP e4m3 byte -> float (decoder, epilogue only)
__device__ __forceinline__ float fp8_to_f(unsigned b) {
    const unsigned s = b >> 7, e = (b >> 3) & 15, m = b & 7;
    const int ee = e ? (int)e : 1;
    const int mm = e ? (int)(8 + m) : (int)m;
    union { unsigned u; float f; } sc; sc.u = (unsigned)(ee + 117) << 23; // 2^(ee-10)
    const float v = (float)mm * sc.f;
    return s ? -v : v;
}
// pack 8 floats -> 8 fp8 e4m3 bytes (saturating RNE via HW cvt)
__device__ __forceinline__ uint2 pk8fp8(float a0, float a1, float a2, float a3,
                                        float a4, float a5, float a6, float a7) {
    uint2 r;
    int w0 = __builtin_amdgcn_cvt_pk_fp8_f32(a0, a1, 0, false);
    w0 = __builtin_amdgcn_cvt_pk_fp8_f32(a2, a3, w0, true);
    int w1 = __builtin_amdgcn_cvt_pk_fp8_f32(a4, a5, 0, false);
    w1 = __builtin_amdgcn_cvt_pk_fp8_f32(a6, a7, w1, true);
    r.x = (unsigned)w0; r.y = (unsigned)w1;
    return r;
}

#define GLL(gp, lp) __builtin_amdgcn_global_load_lds( \
    (const __attribute__((address_space(1))) void*)(gp), \
    (__attribute__((address_space(3))) void*)(lp), 16, 0, 0)

// ---------- fp32 -> bf16 convert ----------
__global__ __launch_bounds__(256) void cvt_f32_bf16(const float* __restrict__ in,
                                                    bf16* __restrict__ out, int n) {
    int i = (blockIdx.x * 256 + threadIdx.x) * 4;
    if (i + 3 < n) {
        float4 v = *(const float4*)(in + i);
        ushort4 o;
        o.x = (unsigned short)f2bfs(v.x);
        o.y = (unsigned short)f2bfs(v.y);
        o.z = (unsigned short)f2bfs(v.z);
        o.w = (unsigned short)f2bfs(v.w);
        *(ushort4*)(out + i) = o;
    } else {
        for (int k = i; k < n; k++) out[k] = __float2bfloat16(in[k]);
    }
}

// ---------- fp32 -> fp8 e4m3 with x32 pre-scale (weights; MX scale 2^-5 compensates) ----------
__global__ __launch_bounds__(256) void cvt_f32_fp8_w(const float* __restrict__ in,
                                                     unsigned char* __restrict__ out, int n) {
    int i = (blockIdx.x * 256 + threadIdx.x) * 4;
    if (i >= n) return;
    float4 v = *(const float4*)(in + i);
    int w0 = __builtin_amdgcn_cvt_pk_fp8_f32(v.x * 32.f, v.y * 32.f, 0, false);
    w0 = __builtin_amdgcn_cvt_pk_fp8_f32(v.z * 32.f, v.w * 32.f, w0, true);
    *(int*)(out + i) = w0;
}

// ---------- per-batch transpose: Q (B,LQ,DIM) f32 -> Qt (B,DIM,LQ) bf16 ----------
__global__ __launch_bounds__(256) void transpose_q(const float* __restrict__ Q,
                                                   bf16* __restrict__ Qt) {
    __shared__ float t[32][33];
    const int b = blockIdx.z;
    const int q0 = blockIdx.x * 32, d0 = blockIdx.y * 32;
    const int tx = threadIdx.x, ty = threadIdx.y; // 32 x 8
    const float* Qb = Q + (long)b * LQ * DIM;
    bf16* Qtb = Qt + (long)b * DIM * LQ;
#pragma unroll
    for (int i = 0; i < 32; i += 8)
        t[ty + i][tx] = Qb[(long)(q0 + ty + i) * DIM + d0 + tx];
    __syncthreads();
#pragma unroll
    for (int i = 0; i < 32; i += 8)
        Qtb[(long)(d0 + ty + i) * LQ + q0 + tx] = __float2bfloat16(t[tx][ty + i]);
}

// ---------- generic bf16 MFMA GEMM: Out[M,N] = A[M,K] @ B[N,K]^T ----------
enum { MODE_PLAIN = 0, MODE_BIAS_LRELU = 1 };

template <int MODE>
__global__ __launch_bounds__(256)
void gemm_bt(const bf16* __restrict__ A, const bf16* __restrict__ B,
             void* __restrict__ Out,
             const float* __restrict__ bias,
             int N, int K,
             long strideA, long strideB, long strideO) {
    constexpr int BM = 128, BN = 128, BK = 32;
    __shared__ __align__(16) bf16 As[BM * BK];
    __shared__ __align__(16) bf16 Bs[BN * BK];

    const int z = blockIdx.z;
    const bf16* Ab = A + (long)z * strideA;
    const bf16* Bb = B + (long)z * strideB;

    const int tid = threadIdx.x;
    const int wave = tid >> 6, lane = tid & 63;
    const int wm = (wave >> 1) * 64, wn = (wave & 1) * 64;
    const int lrow = lane & 15, lq = lane >> 4;

    const int bm0 = blockIdx.y * BM;
    const int bn0 = blockIdx.x * BN;

    const int srow = tid >> 2;
    const int scol = (tid & 3) * 8;

    const bf16* ag = Ab + (long)(bm0 + srow) * K + scol;
    const bf16* bg = Bb + (long)(bn0 + srow) * K + scol;
    bf16* asl = &As[srow * BK + scol];   // byte offset = tid*16: contiguous in lane order
    bf16* bsl = &Bs[srow * BK + scol];
    const long skip64 = (long)64 * K;

    f32x4 acc[4][4];
#pragma unroll
    for (int i = 0; i < 4; i++)
#pragma unroll
        for (int j = 0; j < 4; j++) acc[i][j] = (f32x4){0.f, 0.f, 0.f, 0.f};

    for (int k0 = 0; k0 < K; k0 += BK) {
        GLL(ag, asl);
        GLL(ag + skip64, asl + 64 * BK);
        GLL(bg, bsl);
        GLL(bg + skip64, bsl + 64 * BK);
        ag += BK; bg += BK;
        __syncthreads();

        s16x8 af[4], bfv[4];
#pragma unroll
        for (int f = 0; f < 4; f++)
            af[f] = *(const s16x8*)&As[(wm + f * 16 + lrow) * BK + lq * 8];
#pragma unroll
        for (int f = 0; f < 4; f++)
            bfv[f] = *(const s16x8*)&Bs[(wn + f * 16 + lrow) * BK + lq * 8];

#pragma unroll
        for (int i = 0; i < 4; i++)
#pragma unroll
            for (int j = 0; j < 4; j++)
                acc[i][j] = __builtin_amdgcn_mfma_f32_16x16x32_bf16(af[i], bfv[j], acc[i][j], 0, 0, 0);
        __syncthreads();
    }

    // epilogue: C/D layout col=lane&15, row=(lane>>4)*4+reg  [m89/m91-verified]
#pragma unroll
    for (int i = 0; i < 4; i++) {
#pragma unroll
        for (int j = 0; j < 4; j++) {
            const int n = bn0 + wn + j * 16 + lrow;
            const float bn_bias = (MODE == MODE_PLAIN) ? 0.f : bias[n];
#pragma unroll
            for (int r = 0; r < 4; r++) {
                const int m = bm0 + wm + i * 16 + lq * 4 + r;
                const long off = (long)z * strideO + (long)m * N + n;
                float v = acc[i][j][r];
                if (MODE == MODE_PLAIN) {
                    ((bf16*)Out)[off] = __float2bfloat16(v);
                } else { // MODE_BIAS_LRELU
                    v += bn_bias;
                    v = v > 0.f ? v : 0.01f * v;
                    ((bf16*)Out)[off] = __float2bfloat16(v);
                }
            }
        }
    }
}

// ---------- fused dual GEMM, MX-fp8 K=128, double-buffered 2-phase pipeline ----------
// fuse = tanh(cat@Wf^T+bf), gate = sigm(cat@Wg^T+bg),
// out = Cmask ? g*fuse+(1-g)*cat : -1e30
// A = cat fp8 (scale 2^0, byte 127); B = weights pre-scaled x32 fp8 (MX scale 2^-5, byte 122).
//
// Round-1 post-mortem: 512-thread (8-wave) block caps unified VGPR+AGPR at 256 ->
// 128 acc + 32 af + 16 b + addressing spilled to scratch (WRITE_SIZE 5.6 GB).
// Fix: keep round-0 geometry (256 thr / 4 waves, 128x128 tile, per-wave 64x64,
// VGPR cap 512 at 1 wave/SIMD) and add ONLY the 2-phase double-buffer:
//   loop: STAGE(t+1) issued first -> ds_read+MFMA on tile t -> __syncthreads
// (one vmcnt(0) drain per tile, issued ~1100 cy of MFMA before the wait).
// LDS = 2 x 48 KiB = 96 KiB -> 1 block/CU; 4 waves sit on 4 different SIMDs so
// no intra-tile barriers / setprio (nothing to arbitrate).
// LDS tiles: 16B chunks XOR-swizzled: chunk c of row m at pos c^(m&7) — keeps
// global_load_lds lane-contiguous AND makes fragment ds_reads 2-way-only = free.
__global__ __launch_bounds__(256, 1)
void gemm_dual_fp8(const unsigned char* __restrict__ A8,
                   const unsigned char* __restrict__ Bf8,
                   const unsigned char* __restrict__ Bg8,
                   float* __restrict__ Out,
                   const float* __restrict__ biasf, const float* __restrict__ biasg,
                   const unsigned char* __restrict__ cat8,
                   const int* __restrict__ cmask) {
    constexpr int BM = 128, BN = 128;
    constexpr int N = FEAT, K = FEAT;   // K in bytes per row (fp8)
    constexpr int BUF = 49152;          // per buffer: A 16K | Bf 16K | Bg 16K
    __shared__ __align__(16) char lds[2 * BUF];

    const int tid = threadIdx.x;
    const int wave = tid >> 6, lane = tid & 63;
    const int wm = (wave >> 1) * 64, wn = (wave & 1) * 64;
    const int lrow = lane & 15, lq = lane >> 4;

    const int bm0 = blockIdx.y * BM;
    const int bn0 = blockIdx.x * BN;

    // ---- staging: thread t writes LDS chunk at byte tid*16 of a 4KB round (32 rows);
    // that chunk holds global row r0(+32r), k-bytes (p ^ (r0&7))*16 .. +16 ----
    const int p = tid & 7, r0 = tid >> 3;        // r0: 0..31
    const int xo = (p ^ (r0 & 7)) * 16;
    const long Kl = K;
    const unsigned char* agp = A8 + (long)(bm0 + r0) * Kl + xo;
    const unsigned char* bfgp = Bf8 + (long)(bn0 + r0) * Kl + xo;
    const unsigned char* bggp = Bg8 + (long)(bn0 + r0) * Kl + xo;
    const long rowskip = (long)32 * Kl;

#define STAGE12(bufp, koff) do {                                        \
        char* _ab = (bufp);                                             \
        GLL(agp + (koff), _ab + tid * 16);                              \
        GLL(agp + (koff) + rowskip, _ab + 4096 + tid * 16);             \
        GLL(agp + (koff) + 2 * rowskip, _ab + 8192 + tid * 16);         \
        GLL(agp + (koff) + 3 * rowskip, _ab + 12288 + tid * 16);        \
        GLL(bfgp + (koff), _ab + 16384 + tid * 16);                     \
        GLL(bfgp + (koff) + rowskip, _ab + 20480 + tid * 16);           \
        GLL(bfgp + (koff) + 2 * rowskip, _ab + 24576 + tid * 16);       \
        GLL(bfgp + (koff) + 3 * rowskip, _ab + 28672 + tid * 16);       \
        GLL(bggp + (koff), _ab + 32768 + tid * 16);                     \
        GLL(bggp + (koff) + rowskip, _ab + 36864 + tid * 16);           \
        GLL(bggp + (koff) + 2 * rowskip, _ab + 40960 + tid * 16);       \
        GLL(bggp + (koff) + 3 * rowskip, _ab + 45056 + tid * 16);       \
    } while (0)

    // ---- fragment ds_read offsets (loop-invariant): frag (row, kq=lq) half h
    // stored at row*128 + ((lq*2+h)^(row&7))*16; note off(h=1) = off(h=0) ^ 16 ----
    int offA[4], offB[4];
#pragma unroll
    for (int f = 0; f < 4; f++) {
        const int ra = wm + f * 16 + lrow;
        offA[f] = ra * 128 + (((lq * 2) ^ (ra & 7)) * 16);
        const int rb = wn + f * 16 + lrow;
        offB[f] = rb * 128 + (((lq * 2) ^ (rb & 7)) * 16);
    }

    f32x4 accf[4][4], accg[4][4];
#pragma unroll
    for (int i = 0; i < 4; i++)
#pragma unroll
        for (int j = 0; j < 4; j++) {
            accf[i][j] = (f32x4){0.f, 0.f, 0.f, 0.f};
            accg[i][j] = (f32x4){0.f, 0.f, 0.f, 0.f};
        }

    // prologue: stage tile 0 into buf 0; barrier drains vmcnt(0)
    STAGE12(lds, 0);
    __syncthreads();

    constexpr int NT = K / 128;   // 16 K-tiles
    for (int kt = 0; kt < NT; ++kt) {
        const char* cb = lds + (kt & 1) * BUF;    // compute buffer
        char* nb = lds + ((kt & 1) ^ 1) * BUF;    // stage target (free: all waves passed
                                                  // the barrier that ended its compute)
        // issue next-tile loads FIRST — they fly under this tile's ds_read + MFMA
        if (kt + 1 < NT) STAGE12(nb, (long)(kt + 1) * 128);

        const char* Asb = cb;
        const char* Bfb = cb + 16384;
        const char* Bgb = cb + 32768;

        i32x8 af[4];
#pragma unroll
        for (int f = 0; f < 4; f++) {
            const i32x4 lo = *(const i32x4*)(Asb + offA[f]);
            const i32x4 hi = *(const i32x4*)(Asb + (offA[f] ^ 16));
            af[f][0] = lo[0]; af[f][1] = lo[1]; af[f][2] = lo[2]; af[f][3] = lo[3];
            af[f][4] = hi[0]; af[f][5] = hi[1]; af[f][6] = hi[2]; af[f][7] = hi[3];
        }
#pragma unroll
        for (int j = 0; j < 4; j++) {
            i32x8 bfj, bgj;
            {
                const i32x4 lo = *(const i32x4*)(Bfb + offB[j]);
                const i32x4 hi = *(const i32x4*)(Bfb + (offB[j] ^ 16));
                bfj[0] = lo[0]; bfj[1] = lo[1]; bfj[2] = lo[2]; bfj[3] = lo[3];
                bfj[4] = hi[0]; bfj[5] = hi[1]; bfj[6] = hi[2]; bfj[7] = hi[3];
            }
            {
                const i32x4 lo = *(const i32x4*)(Bgb + offB[j]);
                const i32x4 hi = *(const i32x4*)(Bgb + (offB[j] ^ 16));
                bgj[0] = lo[0]; bgj[1] = lo[1]; bgj[2] = lo[2]; bgj[3] = lo[3];
                bgj[4] = hi[0]; bgj[5] = hi[1]; bgj[6] = hi[2]; bgj[7] = hi[3];
            }
#pragma unroll
            for (int i = 0; i < 4; i++)
                accf[i][j] = __builtin_amdgcn_mfma_scale_f32_16x16x128_f8f6f4(
                    af[i], bfj, accf[i][j], 0, 0, 0, 127, 0, 122);
#pragma unroll
            for (int i = 0; i < 4; i++)
                accg[i][j] = __builtin_amdgcn_mfma_scale_f32_16x16x128_f8f6f4(
                    af[i], bgj, accg[i][j], 0, 0, 0, 127, 0, 122);
        }
        // tile boundary: drain vmcnt (tile t+1 resident) + LDS reuse fence
        __syncthreads();
    }
#undef STAGE12

    // epilogue: C/D layout col=lane&15, row=(lane>>4)*4+reg (shape-determined)
#pragma unroll
    for (int j = 0; j < 4; j++) {
        const int n = bn0 + wn + j * 16 + lrow;
        const float bfb = biasf[n];
        const float bgb = biasg[n];
#pragma unroll
        for (int i = 0; i < 4; i++) {
#pragma unroll
            for (int r = 0; r < 4; r++) {
                const int m = bm0 + wm + i * 16 + lq * 4 + r;
                const long off = (long)m * N + n;
                const float vf = accf[i][j][r] + bfb;
                const float vg = accg[i][j][r] + bgb;
                const float e = __expf(2.0f * fabsf(vf));
                const float th = copysignf(1.0f - 2.0f / (e + 1.0f), vf);
                const float g = 1.0f / (1.0f + __expf(-vg));
                const float c = fp8_to_f(cat8[off]);
                Out[off] = cmask[m] ? (g * th + (1.0f - g) * c) : NEG_INF_F;
            }
        }
    }
}

// ---------- masked row softmax over LQ=512, in place on bf16 S ----------
__global__ __launch_bounds__(256) void softmax_rows(bf16* __restrict__ S,
                                                    const int* __restrict__ Cmask,
                                                    const int* __restrict__ Qmask) {
    const int row = blockIdx.x;         // 0 .. B*LC-1
    const int b = row >> 11;            // LC = 2048
    const int tid = threadIdx.x;
    bf16* srow = S + (long)row * LQ;
    const int* qm = Qmask + b * LQ;
    __shared__ float red[8];

    if (Cmask[row] == 0) {
        const bf16 u = __float2bfloat16(1.0f / 512.0f);
        srow[tid] = u;
        srow[tid + 256] = u;
        return;
    }
    const int q0 = qm[tid], q1 = qm[tid + 256];
    float v0 = q0 ? __bfloat162float(srow[tid]) : -3e38f;
    float v1 = q1 ? __bfloat162float(srow[tid + 256]) : -3e38f;
    float mx = fmaxf(v0, v1);
#pragma unroll
    for (int o = 32; o > 0; o >>= 1) mx = fmaxf(mx, __shfl_down(mx, o, 64));
    const int wave = tid >> 6, lane = tid & 63;
    if (lane == 0) red[wave] = mx;
    __syncthreads();
    const float m4 = fmaxf(fmaxf(red[0], red[1]), fmaxf(red[2], red[3]));
    float e0 = q0 ? __expf(v0 - m4) : 0.f;
    float e1 = q1 ? __expf(v1 - m4) : 0.f;
    float s = e0 + e1;
#pragma unroll
    for (int o = 32; o > 0; o >>= 1) s += __shfl_down(s, o, 64);
    if (lane == 0) red[4 + wave] = s;
    __syncthreads();
    const float tot = red[4] + red[5] + red[6] + red[7];
    if (!(tot > 0.f)) {
        const bf16 u = __float2bfloat16(1.0f / 512.0f);
        srow[tid] = u;
        srow[tid + 256] = u;
        return;
    }
    const float inv = 1.0f / tot;
    srow[tid] = __float2bfloat16(e0 * inv);
    srow[tid + 256] = __float2bfloat16(e1 * inv);
}

// ---------- build cat = [C | attn | attn-C | attn*C] as fp8 e4m3 ----------
__global__ __launch_bounds__(256) void build_cat(const bf16* __restrict__ Cb,
                                                 const bf16* __restrict__ attn,
                                                 unsigned char* __restrict__ cat8) {
    const long t = (long)blockIdx.x * 256 + threadIdx.x;
    const int m = (int)(t >> 6);
    const int c = (int)(t & 63) << 3;
    const s16x8 cv = *(const s16x8*)((const short*)Cb + (long)m * DIM + c);
    const s16x8 av = *(const s16x8*)((const short*)attn + (long)m * DIM + c);
    float cf[8], af_[8];
#pragma unroll
    for (int i = 0; i < 8; i++) { cf[i] = bfs2f(cv[i]); af_[i] = bfs2f(av[i]); }
    unsigned char* rowp = cat8 + (long)m * FEAT + c;
    *(uint2*)(rowp) = pk8fp8(cf[0], cf[1], cf[2], cf[3], cf[4], cf[5], cf[6], cf[7]);
    *(uint2*)(rowp + 512) = pk8fp8(af_[0], af_[1], af_[2], af_[3], af_[4], af_[5], af_[6], af_[7]);
    *(uint2*)(rowp + 1024) = pk8fp8(af_[0] - cf[0], af_[1] - cf[1], af_[2] - cf[2], af_[3] - cf[3],
                                    af_[4] - cf[4], af_[5] - cf[5], af_[6] - cf[6], af_[7] - cf[7]);
    *(uint2*)(rowp + 1536) = pk8fp8(af_[0] * cf[0], af_[1] * cf[1], af_[2] * cf[2], af_[3] * cf[3],
                                    af_[4] * cf[4], af_[5] * cf[5], af_[6] * cf[6], af_[7] * cf[7]);
}

extern "C" void kernel_launch(void* const* d_in, const int* in_sizes, int n_in,
                              void* d_out, int out_size, void* d_ws, size_t ws_size,
                              hipStream_t stream) {
    (void)in_sizes; (void)n_in; (void)out_size; (void)ws_size;
    const float* C = (const float*)d_in[0];
    const float* Q = (const float*)d_in[1];
    const int* Cmask = (const int*)d_in[2];
    const int* Qmask = (const int*)d_in[3];
    const float* W1 = (const float*)d_in[4];
    const float* b1 = (const float*)d_in[5];
    const float* Wf = (const float*)d_in[6];
    const float* bfp = (const float*)d_in[7];
    const float* Wg = (const float*)d_in[8];
    const float* bgp = (const float*)d_in[9];
    float* out = (float*)d_out;

    // ---- workspace layout (bytes). cat8 overlaps the dead early temps
    // (W1b/Qb/Qt/C_/Q_/S are all last read before build_cat writes cat8). ----
    char* ws = (char*)d_ws;
    unsigned char* cat8 = (unsigned char*)(ws + 0);     //  67,108,864
    bf16* W1b  = (bf16*)(ws + 0);                       //     524,288
    bf16* Qb   = (bf16*)(ws + 524288);                  //   8,388,608
    bf16* Qt   = (bf16*)(ws + 8912896);                 //   8,388,608
    bf16* C_   = (bf16*)(ws + 17301504);                //  33,554,432
    bf16* Q_   = (bf16*)(ws + 50855936);                //   8,388,608
    bf16* S    = (bf16*)(ws + 59244544);                //  33,554,432 (dead before cat8 write)
    bf16* Cb   = (bf16*)(ws + 134217728);               //  33,554,432
    bf16* attn = (bf16*)(ws + 167772160);               //  33,554,432
    unsigned char* Wf8 = (unsigned char*)(ws + 201326592); // 4,194,304
    unsigned char* Wg8 = (unsigned char*)(ws + 205520896); // 4,194,304 (end ~209.7MB)

    // 1. dtype conversions
    cvt_f32_bf16<<<256, 256, 0, stream>>>(W1, W1b, DIM * DIM);
    cvt_f32_fp8_w<<<4096, 256, 0, stream>>>(Wf, Wf8, FEAT * FEAT);
    cvt_f32_fp8_w<<<4096, 256, 0, stream>>>(Wg, Wg8, FEAT * FEAT);
    cvt_f32_bf16<<<16384, 256, 0, stream>>>(C, Cb, MC * DIM);
    cvt_f32_bf16<<<4096, 256, 0, stream>>>(Q, Qb, MQ * DIM);
    transpose_q<<<dim3(16, 16, 16), dim3(32, 8), 0, stream>>>(Q, Qt);

    // 2. C_ = lrelu(C @ W1^T + b1), Q_ = lrelu(Q @ W1^T + b1)  (bf16 out)
    gemm_bt<MODE_BIAS_LRELU><<<dim3(4, 256, 1), 256, 0, stream>>>(
        Cb, W1b, C_, b1, DIM, DIM, 0, 0, 0);
    gemm_bt<MODE_BIAS_LRELU><<<dim3(4, 64, 1), 256, 0, stream>>>(
        Qb, W1b, Q_, b1, DIM, DIM, 0, 0, 0);

    // 3. S[b] = C_[b] @ Q_[b]^T  (batched, bf16 logits)
    gemm_bt<MODE_PLAIN><<<dim3(4, 16, 16), 256, 0, stream>>>(
        C_, Q_, S, nullptr, LQ, DIM,
        (long)LC * DIM, (long)LQ * DIM, (long)LC * LQ);

    // 4. masked softmax over q (in place)
    softmax_rows<<<MC, 256, 0, stream>>>(S, Cmask, Qmask);

    // 5. attn[b] = S[b] @ Q[b]   (B-operand = Qt, batched)
    gemm_bt<MODE_PLAIN><<<dim3(4, 16, 16), 256, 0, stream>>>(
        S, Qt, attn, nullptr, DIM, LQ,
        (long)LC * LQ, (long)DIM * LQ, (long)LC * DIM);

    // 6. cat8 = [C | attn | attn-C | attn*C] (fp8)
    build_cat<<<8192, 256, 0, stream>>>(Cb, attn, cat8);

    // 7+8 fused MX-fp8 dual GEMM + activations + gate blend + Cmask (fp32 out)
    gemm_dual_fp8<<<dim3(16, 256, 1), 256, 0, stream>>>(
        cat8, Wf8, Wg8, out, bfp, bgp, cat8, Cmask);
}

// Round 3
// 1022.347 us; speedup vs baseline: 5.4310x; 4.1040x over previous
//
#include <hip/hip_runtime.h>
#include <hip/hip_bf16.h>
#include <math.h>

using bf16 = __hip_bfloat16;
typedef __attribute__((ext_vector_type(8))) short s16x8;
typedef __attribute__((ext_vector_type(4))) float f32x4;
typedef __attribute__((ext_vector_type(8))) int i32x8;
typedef __attribute__((ext_vector_type(4))) int i32x4;

#define NEG_INF_F (-1e30f)

// ---------- constants for this problem ----------
static constexpr int BATCH = 16;
static constexpr int LC = 2048;
static constexpr int LQ = 512;
static constexpr int DIM = 512;
static constexpr int FEAT = 2048;          // 4*DIM
static constexpr int MC = BATCH * LC;      // 32768
static constexpr int MQ = BATCH * LQ;      // 8192

__device__ __forceinline__ float bfs2f(short s) {
    union { float f; unsigned u; } x;
    x.u = ((unsigned)(unsigned short)s) << 16;
    return x.f;
}
__device__ __forceinline__ short f2bfs(float f) {
    bf16 h = __float2bfloat16(f);
    short s; __builtin_memcpy(&s, &h, 2);
    return s;
}
// OCP e4m3 byte -> float (decoder, epilogue only)
__device__ __forceinline__ float fp8_to_f(unsigned b) {
    const unsigned s = b >> 7, e = (b >> 3) & 15, m = b & 7;
    const int ee = e ? (int)e : 1;
    const int mm = e ? (int)(8 + m) : (int)m;
    union { unsigned u; float f; } sc; sc.u = (unsigned)(ee + 117) << 23; // 2^(ee-10)
    const float v = (float)mm * sc.f;
    return s ? -v : v;
}
// pack 8 floats -> 8 fp8 e4m3 bytes (saturating RNE via HW cvt)
__device__ __forceinline__ uint2 pk8fp8(float a0, float a1, float a2, float a3,
                                        float a4, float a5, float a6, float a7) {
    uint2 r;
    int w0 = __builtin_amdgcn_cvt_pk_fp8_f32(a0, a1, 0, false);
    w0 = __builtin_amdgcn_cvt_pk_fp8_f32(a2, a3, w0, true);
    int w1 = __builtin_amdgcn_cvt_pk_fp8_f32(a4, a5, 0, false);
    w1 = __builtin_amdgcn_cvt_pk_fp8_f32(a6, a7, w1, true);
    r.x = (unsigned)w0; r.y = (unsigned)w1;
    return r;
}

#define GLL(gp, lp) __builtin_amdgcn_global_load_lds( \
    (const __attribute__((address_space(1))) void*)(gp), \
    (__attribute__((address_space(3))) void*)(lp), 16, 0, 0)

// ---------- fp32 -> bf16 convert ----------
__global__ __launch_bounds__(256) void cvt_f32_bf16(const float* __restrict__ in,
                                                    bf16* __restrict__ out, int n) {
    int i = (blockIdx.x * 256 + threadIdx.x) * 4;
    if (i + 3 < n) {
        float4 v = *(const float4*)(in + i);
        ushort4 o;
        o.x = (unsigned short)f2bfs(v.x);
        o.y = (unsigned short)f2bfs(v.y);
        o.z = (unsigned short)f2bfs(v.z);
        o.w = (unsigned short)f2bfs(v.w);
        *(ushort4*)(out + i) = o;
    } else {
        for (int k = i; k < n; k++) out[k] = __float2bfloat16(in[k]);
    }
}

// ---------- fp32 -> fp8 e4m3 with x32 pre-scale (weights; MX scale 2^-5 compensates) ----------
__global__ __launch_bounds__(256) void cvt_f32_fp8_w(const float* __restrict__ in,
                                                     unsigned char* __restrict__ out, int n) {
    int i = (blockIdx.x * 256 + threadIdx.x) * 4;
    if (i >= n) return;
    float4 v = *(const float4*)(in + i);
    int w0 = __builtin_amdgcn_cvt_pk_fp8_f32(v.x * 32.f, v.y * 32.f, 0, false);
    w0 = __builtin_amdgcn_cvt_pk_fp8_f32(v.z * 32.f, v.w * 32.f, w0, true);
    *(int*)(out + i) = w0;
}

// ---------- per-batch transpose: Q (B,LQ,DIM) f32 -> Qt (B,DIM,LQ) bf16 ----------
__global__ __launch_bounds__(256) void transpose_q(const float* __restrict__ Q,
                                                   bf16* __restrict__ Qt) {
    __shared__ float t[32][33];
    const int b = blockIdx.z;
    const int q0 = blockIdx.x * 32, d0 = blockIdx.y * 32;
    const int tx = threadIdx.x, ty = threadIdx.y; // 32 x 8
    const float* Qb = Q + (long)b * LQ * DIM;
    bf16* Qtb = Qt + (long)b * DIM * LQ;
#pragma unroll
    for (int i = 0; i < 32; i += 8)
        t[ty + i][tx] = Qb[(long)(q0 + ty + i) * DIM + d0 + tx];
    __syncthreads();
#pragma unroll
    for (int i = 0; i < 32; i += 8)
        Qtb[(long)(d0 + ty + i) * LQ + q0 + tx] = __float2bfloat16(t[tx][ty + i]);
}

// ---------- generic bf16 MFMA GEMM: Out[M,N] = A[M,K] @ B[N,K]^T ----------
enum { MODE_PLAIN = 0, MODE_BIAS_LRELU = 1 };

template <int MODE>
__global__ __launch_bounds__(256)
void gemm_bt(const bf16* __restrict__ A, const bf16* __restrict__ B,
             void* __restrict__ Out,
             const float* __restrict__ bias,
             int N, int K,
             long strideA, long strideB, long strideO) {
    constexpr int BM = 128, BN = 128, BK = 32;
    __shared__ __align__(16) bf16 As[BM * BK];
    __shared__ __align__(16) bf16 Bs[BN * BK];

    const int z = blockIdx.z;
    const bf16* Ab = A + (long)z * strideA;
    const bf16* Bb = B + (long)z * strideB;

    const int tid = threadIdx.x;
    const int wave = tid >> 6, lane = tid & 63;
    const int wm = (wave >> 1) * 64, wn = (wave & 1) * 64;
    const int lrow = lane & 15, lq = lane >> 4;

    const int bm0 = blockIdx.y * BM;
    const int bn0 = blockIdx.x * BN;

    const int srow = tid >> 2;
    const int scol = (tid & 3) * 8;

    const bf16* ag = Ab + (long)(bm0 + srow) * K + scol;
    const bf16* bg = Bb + (long)(bn0 + srow) * K + scol;
    bf16* asl = &As[srow * BK + scol];   // byte offset = tid*16: contiguous in lane order
    bf16* bsl = &Bs[srow * BK + scol];
    const long skip64 = (long)64 * K;

    f32x4 acc[4][4];
#pragma unroll
    for (int i = 0; i < 4; i++)
#pragma unroll
        for (int j = 0; j < 4; j++) acc[i][j] = (f32x4){0.f, 0.f, 0.f, 0.f};

    for (int k0 = 0; k0 < K; k0 += BK) {
        GLL(ag, asl);
        GLL(ag + skip64, asl + 64 * BK);
        GLL(bg, bsl);
        GLL(bg + skip64, bsl + 64 * BK);
        ag += BK; bg += BK;
        __syncthreads();

        s16x8 af[4], bfv[4];
#pragma unroll
        for (int f = 0; f < 4; f++)
            af[f] = *(const s16x8*)&As[(wm + f * 16 + lrow) * BK + lq * 8];
#pragma unroll
        for (int f = 0; f < 4; f++)
            bfv[f] = *(const s16x8*)&Bs[(wn + f * 16 + lrow) * BK + lq * 8];

#pragma unroll
        for (int i = 0; i < 4; i++)
#pragma unroll
            for (int j = 0; j < 4; j++)
                acc[i][j] = __builtin_amdgcn_mfma_f32_16x16x32_bf16(af[i], bfv[j], acc[i][j], 0, 0, 0);
        __syncthreads();
    }

    // epilogue: C/D layout col=lane&15, row=(lane>>4)*4+reg  [m89/m91-verified]
#pragma unroll
    for (int i = 0; i < 4; i++) {
#pragma unroll
        for (int j = 0; j < 4; j++) {
            const int n = bn0 + wn + j * 16 + lrow;
            const float bn_bias = (MODE == MODE_PLAIN) ? 0.f : bias[n];
#pragma unroll
            for (int r = 0; r < 4; r++) {
                const int m = bm0 + wm + i * 16 + lq * 4 + r;
                const long off = (long)z * strideO + (long)m * N + n;
                float v = acc[i][j][r];
                if (MODE == MODE_PLAIN) {
                    ((bf16*)Out)[off] = __float2bfloat16(v);
                } else { // MODE_BIAS_LRELU
                    v += bn_bias;
                    v = v > 0.f ? v : 0.01f * v;
                    ((bf16*)Out)[off] = __float2bfloat16(v);
                }
            }
        }
    }
}

// ---------- fused dual GEMM, MX-fp8 K=128, 2-phase double buffer ----------
// fuse = tanh(cat@Wf^T+bf), gate = sigm(cat@Wg^T+bg),
// out = Cmask ? g*fuse+(1-g)*cat : -1e30
// A = cat fp8 (scale 2^0, byte 127); B = weights pre-scaled x32 fp8 (MX scale 2^-5, byte 122).
//
// Register-allocation discipline (rounds 1-2 post-mortem): this body fits ONLY
// under the round-0 conditions — launch_bounds(256,2) (cap 256 unified regs,
// compiler puts the 128 acc in AGPRs; measured 108 arch VGPRs) and
// compile-time-constant LDS bases. Round 1 (8 waves) and round 2
// (launch_bounds(256,1) + runtime buffer base + unrollable loop) both spilled
// to multi-GB scratch (VGPR_Count 128/256, WRITE_SIZE 4.5-5.6 GB).
// So: two hard-coded buffer halves, loop steps 2 K-tiles/iter,
// unroll(disable) to forbid the software-pipelining that exploded liveness.
// Per phase: STAGE(other buffer, tile t+1) -> ds_read + 32 MFMA on this buffer
// (~1100 cy matrix-pipe) -> __syncthreads (the only vmcnt drain, after the
// MFMA shadow). LDS 96 KiB -> 1 block/CU, 1 wave/SIMD: a wave's 32 independent
// MFMAs keep the pipe busy while it issues next-tile ds_reads, so 1 wave/SIMD
// suffices for an MFMA-bound loop with no mid-tile drain.
// LDS tiles: 16B chunks XOR-swizzled: chunk c of row m at pos c^(m&7) — keeps
// global_load_lds lane-contiguous AND makes fragment ds_reads 2-way-only = free.
__global__ __launch_bounds__(256, 2)
void gemm_dual_fp8(const unsigned char* __restrict__ A8,
                   const unsigned char* __restrict__ Bf8,
                   const unsigned char* __restrict__ Bg8,
                   float* __restrict__ Out,
                   const float* __restrict__ biasf, const float* __restrict__ biasg,
                   const unsigned char* __restrict__ cat8,
                   const int* __restrict__ cmask) {
    constexpr int BM = 128, BN = 128;
    constexpr int N = FEAT, K = FEAT;   // K in bytes per row (fp8)
    constexpr int BUF = 49152;          // per buffer: A 16K | Bf 16K | Bg 16K
    __shared__ __align__(16) char lds[2 * BUF];

    const int tid = threadIdx.x;
    const int wave = tid >> 6, lane = tid & 63;
    const int wm = (wave >> 1) * 64, wn = (wave & 1) * 64;
    const int lrow = lane & 15, lq = lane >> 4;

    const int bm0 = blockIdx.y * BM;
    const int bn0 = blockIdx.x * BN;

    // ---- staging: thread t writes LDS chunk at byte tid*16 of a 4KB round (32 rows);
    // that chunk holds global row r0(+32r), k-bytes (p ^ (r0&7))*16 .. +16 ----
    const int p = tid & 7, r0 = tid >> 3;        // r0: 0..31
    const int xo = (p ^ (r0 & 7)) * 16;
    const long Kl = K;
    const unsigned char* agp = A8 + (long)(bm0 + r0) * Kl + xo;
    const unsigned char* bfgp = Bf8 + (long)(bn0 + r0) * Kl + xo;
    const unsigned char* bggp = Bg8 + (long)(bn0 + r0) * Kl + xo;
    const long rowskip = (long)32 * Kl;

#define STAGE12(bufbase, koff) do {                                     \
        char* _ab = (bufbase);                                          \
        GLL(agp + (koff), _ab + tid * 16);                              \
        GLL(agp + (koff) + rowskip, _ab + 4096 + tid * 16);             \
        GLL(agp + (koff) + 2 * rowskip, _ab + 8192 + tid * 16);         \
        GLL(agp + (koff) + 3 * rowskip, _ab + 12288 + tid * 16);        \
        GLL(bfgp + (koff), _ab + 16384 + tid * 16);                     \
        GLL(bfgp + (koff) + rowskip, _ab + 20480 + tid * 16);           \
        GLL(bfgp + (koff) + 2 * rowskip, _ab + 24576 + tid * 16);       \
        GLL(bfgp + (koff) + 3 * rowskip, _ab + 28672 + tid * 16);       \
        GLL(bggp + (koff), _ab + 32768 + tid * 16);                     \
        GLL(bggp + (koff) + rowskip, _ab + 36864 + tid * 16);           \
        GLL(bggp + (koff) + 2 * rowskip, _ab + 40960 + tid * 16);       \
        GLL(bggp + (koff) + 3 * rowskip, _ab + 45056 + tid * 16);       \
    } while (0)

    // ---- fragment ds_read offsets (loop-invariant): frag (row, kq=lq) half h
    // stored at row*128 + ((lq*2+h)^(row&7))*16; note off(h=1) = off(h=0) ^ 16 ----
    int offA[4], offB[4];
#pragma unroll
    for (int f = 0; f < 4; f++) {
        const int ra = wm + f * 16 + lrow;
        offA[f] = ra * 128 + (((lq * 2) ^ (ra & 7)) * 16);
        const int rb = wn + f * 16 + lrow;
        offB[f] = rb * 128 + (((lq * 2) ^ (rb & 7)) * 16);
    }

    f32x4 accf[4][4], accg[4][4];
#pragma unroll
    for (int i = 0; i < 4; i++)
#pragma unroll
        for (int j = 0; j < 4; j++) {
            accf[i][j] = (f32x4){0.f, 0.f, 0.f, 0.f};
            accg[i][j] = (f32x4){0.f, 0.f, 0.f, 0.f};
        }

    // one K-tile compute on a compile-time-constant buffer base
#define COMPUTE(bufbase) do {                                               \
        const char* Asb = (bufbase);                                        \
        const char* Bfb = (bufbase) + 16384;                                \
        const char* Bgb = (bufbase) + 32768;                                \
        i32x8 af[4];                                                        \
        _Pragma("unroll")                                                   \
        for (int f = 0; f < 4; f++) {                                       \
            const i32x4 lo = *(const i32x4*)(Asb + offA[f]);                \
            const i32x4 hi = *(const i32x4*)(Asb + (offA[f] ^ 16));         \
            af[f][0] = lo[0]; af[f][1] = lo[1]; af[f][2] = lo[2];           \
            af[f][3] = lo[3]; af[f][4] = hi[0]; af[f][5] = hi[1];           \
            af[f][6] = hi[2]; af[f][7] = hi[3];                             \
        }                                                                   \
        _Pragma("unroll")                                                   \
        for (int j = 0; j < 4; j++) {                                       \
            i32x8 bfj, bgj;                                                 \
            {                                                               \
                const i32x4 lo = *(const i32x4*)(Bfb + offB[j]);            \
                const i32x4 hi = *(const i32x4*)(Bfb + (offB[j] ^ 16));     \
                bfj[0] = lo[0]; bfj[1] = lo[1]; bfj[2] = lo[2];             \
                bfj[3] = lo[3]; bfj[4] = hi[0]; bfj[5] = hi[1];             \
                bfj[6] = hi[2]; bfj[7] = hi[3];                             \
            }                                                               \
            {                                                               \
                const i32x4 lo = *(const i32x4*)(Bgb + offB[j]);            \
                const i32x4 hi = *(const i32x4*)(Bgb + (offB[j] ^ 16));     \
                bgj[0] = lo[0]; bgj[1] = lo[1]; bgj[2] = lo[2];             \
                bgj[3] = lo[3]; bgj[4] = hi[0]; bgj[5] = hi[1];             \
                bgj[6] = hi[2]; bgj[7] = hi[3];                             \
            }                                                               \
            _Pragma("unroll")                                               \
            for (int i = 0; i < 4; i++)                                     \
                accf[i][j] = __builtin_amdgcn_mfma_scale_f32_16x16x128_f8f6f4( \
                    af[i], bfj, accf[i][j], 0, 0, 0, 127, 0, 122);          \
            _Pragma("unroll")                                               \
            for (int i = 0; i < 4; i++)                                     \
                accg[i][j] = __builtin_amdgcn_mfma_scale_f32_16x16x128_f8f6f4( \
                    af[i], bgj, accg[i][j], 0, 0, 0, 127, 0, 122);          \
        }                                                                   \
    } while (0)

    // prologue: stage tile 0 into buf0; barrier drains vmcnt(0)
    STAGE12(lds, 0);
    __syncthreads();

    constexpr int NT = K / 128;   // 16 K-tiles, 2 per iteration
#pragma clang loop unroll(disable)
    for (int kt = 0; kt < NT; kt += 2) {
        // phase A: prefetch tile kt+1 into buf1 (kt+1 <= 15 always), compute buf0
        STAGE12(lds + BUF, (long)(kt + 1) * 128);
        COMPUTE(lds);
        __syncthreads();   // drains vmcnt: buf1 resident; buf0 free to overwrite
        // phase B: prefetch tile kt+2 into buf0, compute buf1
        if (kt + 2 < NT) STAGE12(lds, (long)(kt + 2) * 128);
        COMPUTE(lds + BUF);
        __syncthreads();   // drains vmcnt: buf0 resident; buf1 free to overwrite
    }
#undef STAGE12
#undef COMPUTE

    // epilogue: C/D layout col=lane&15, row=(lane>>4)*4+reg (shape-determined)
#pragma unroll
    for (int j = 0; j < 4; j++) {
        const int n = bn0 + wn + j * 16 + lrow;
        const float bfb = biasf[n];
        const float bgb = biasg[n];
#pragma unroll
        for (int i = 0; i < 4; i++) {
#pragma unroll
            for (int r = 0; r < 4; r++) {
                const int m = bm0 + wm + i * 16 + lq * 4 + r;
                const long off = (long)m * N + n;
                const float vf = accf[i][j][r] + bfb;
                const float vg = accg[i][j][r] + bgb;
                const float e = __expf(2.0f * fabsf(vf));
                const float th = copysignf(1.0f - 2.0f / (e + 1.0f), vf);
                const float g = 1.0f / (1.0f + __expf(-vg));
                const float c = fp8_to_f(cat8[off]);
                Out[off] = cmask[m] ? (g * th + (1.0f - g) * c) : NEG_INF_F;
            }
        }
    }
}

// ---------- masked row softmax over LQ=512, in place on bf16 S ----------
__global__ __launch_bounds__(256) void softmax_rows(bf16* __restrict__ S,
                                                    const int* __restrict__ Cmask,
                                                    const int* __restrict__ Qmask) {
    const int row = blockIdx.x;         // 0 .. B*LC-1
    const int b = row >> 11;            // LC = 2048
    const int tid = threadIdx.x;
    bf16* srow = S + (long)row * LQ;
    const int* qm = Qmask + b * LQ;
    __shared__ float red[8];

    if (Cmask[row] == 0) {
        const bf16 u = __float2bfloat16(1.0f / 512.0f);
        srow[tid] = u;
        srow[tid + 256] = u;
        return;
    }
    const int q0 = qm[tid], q1 = qm[tid + 256];
    float v0 = q0 ? __bfloat162float(srow[tid]) : -3e38f;
    float v1 = q1 ? __bfloat162float(srow[tid + 256]) : -3e38f;
    float mx = fmaxf(v0, v1);
#pragma unroll
    for (int o = 32; o > 0; o >>= 1) mx = fmaxf(mx, __shfl_down(mx, o, 64));
    const int wave = tid >> 6, lane = tid & 63;
    if (lane == 0) red[wave] = mx;
    __syncthreads();
    const float m4 = fmaxf(fmaxf(red[0], red[1]), fmaxf(red[2], red[3]));
    float e0 = q0 ? __expf(v0 - m4) : 0.f;
    float e1 = q1 ? __expf(v1 - m4) : 0.f;
    float s = e0 + e1;
#pragma unroll
    for (int o = 32; o > 0; o >>= 1) s += __shfl_down(s, o, 64);
    if (lane == 0) red[4 + wave] = s;
    __syncthreads();
    const float tot = red[4] + red[5] + red[6] + red[7];
    if (!(tot > 0.f)) {
        const bf16 u = __float2bfloat16(1.0f / 512.0f);
        srow[tid] = u;
        srow[tid + 256] = u;
        return;
    }
    const float inv = 1.0f / tot;
    srow[tid] = __float2bfloat16(e0 * inv);
    srow[tid + 256] = __float2bfloat16(e1 * inv);
}

// ---------- build cat = [C | attn | attn-C | attn*C] as fp8 e4m3 ----------
__global__ __launch_bounds__(256) void build_cat(const bf16* __restrict__ Cb,
                                                 const bf16* __restrict__ attn,
                                                 unsigned char* __restrict__ cat8) {
    const long t = (long)blockIdx.x * 256 + threadIdx.x;
    const int m = (int)(t >> 6);
    const int c = (int)(t & 63) << 3;
    const s16x8 cv = *(const s16x8*)((const short*)Cb + (long)m * DIM + c);
    const s16x8 av = *(const s16x8*)((const short*)attn + (long)m * DIM + c);
    float cf[8], af_[8];
#pragma unroll
    for (int i = 0; i < 8; i++) { cf[i] = bfs2f(cv[i]); af_[i] = bfs2f(av[i]); }
    unsigned char* rowp = cat8 + (long)m * FEAT + c;
    *(uint2*)(rowp) = pk8fp8(cf[0], cf[1], cf[2], cf[3], cf[4], cf[5], cf[6], cf[7]);
    *(uint2*)(rowp + 512) = pk8fp8(af_[0], af_[1], af_[2], af_[3], af_[4], af_[5], af_[6], af_[7]);
    *(uint2*)(rowp + 1024) = pk8fp8(af_[0] - cf[0], af_[1] - cf[1], af_[2] - cf[2], af_[3] - cf[3],
                                    af_[4] - cf[4], af_[5] - cf[5], af_[6] - cf[6], af_[7] - cf[7]);
    *(uint2*)(rowp + 1536) = pk8fp8(af_[0] * cf[0], af_[1] * cf[1], af_[2] * cf[2], af_[3] * cf[3],
                                    af_[4] * cf[4], af_[5] * cf[5], af_[6] * cf[6], af_[7] * cf[7]);
}

extern "C" void kernel_launch(void* const* d_in, const int* in_sizes, int n_in,
                              void* d_out, int out_size, void* d_ws, size_t ws_size,
                              hipStream_t stream) {
    (void)in_sizes; (void)n_in; (void)out_size; (void)ws_size;
    const float* C = (const float*)d_in[0];
    const float* Q = (const float*)d_in[1];
    const int* Cmask = (const int*)d_in[2];
    const int* Qmask = (const int*)d_in[3];
    const float* W1 = (const float*)d_in[4];
    const float* b1 = (const float*)d_in[5];
    const float* Wf = (const float*)d_in[6];
    const float* bfp = (const float*)d_in[7];
    const float* Wg = (const float*)d_in[8];
    const float* bgp = (const float*)d_in[9];
    float* out = (float*)d_out;

    // ---- workspace layout (bytes). cat8 overlaps the dead early temps
    // (W1b/Qb/Qt/C_/Q_/S are all last read before build_cat writes cat8). ----
    char* ws = (char*)d_ws;
    unsigned char* cat8 = (unsigned char*)(ws + 0);     //  67,108,864
    bf16* W1b  = (bf16*)(ws + 0);                       //     524,288
    bf16* Qb   = (bf16*)(ws + 524288);                  //   8,388,608
    bf16* Qt   = (bf16*)(ws + 8912896);                 //   8,388,608
    bf16* C_   = (bf16*)(ws + 17301504);                //  33,554,432
    bf16* Q_   = (bf16*)(ws + 50855936);                //   8,388,608
    bf16* S    = (bf16*)(ws + 59244544);                //  33,554,432 (dead before cat8 write)
    bf16* Cb   = (bf16*)(ws + 134217728);               //  33,554,432
    bf16* attn = (bf16*)(ws + 167772160);               //  33,554,432
    unsigned char* Wf8 = (unsigned char*)(ws + 201326592); // 4,194,304
    unsigned char* Wg8 = (unsigned char*)(ws + 205520896); // 4,194,304 (end ~209.7MB)

    // 1. dtype conversions
    cvt_f32_bf16<<<256, 256, 0, stream>>>(W1, W1b, DIM * DIM);
    cvt_f32_fp8_w<<<4096, 256, 0, stream>>>(Wf, Wf8, FEAT * FEAT);
    cvt_f32_fp8_w<<<4096, 256, 0, stream>>>(Wg, Wg8, FEAT * FEAT);
    cvt_f32_bf16<<<16384, 256, 0, stream>>>(C, Cb, MC * DIM);
    cvt_f32_bf16<<<4096, 256, 0, stream>>>(Q, Qb, MQ * DIM);
    transpose_q<<<dim3(16, 16, 16), dim3(32, 8), 0, stream>>>(Q, Qt);

    // 2. C_ = lrelu(C @ W1^T + b1), Q_ = lrelu(Q @ W1^T + b1)  (bf16 out)
    gemm_bt<MODE_BIAS_LRELU><<<dim3(4, 256, 1), 256, 0, stream>>>(
        Cb, W1b, C_, b1, DIM, DIM, 0, 0, 0);
    gemm_bt<MODE_BIAS_LRELU><<<dim3(4, 64, 1), 256, 0, stream>>>(
        Qb, W1b, Q_, b1, DIM, DIM, 0, 0, 0);

    // 3. S[b] = C_[b] @ Q_[b]^T  (batched, bf16 logits)
    gemm_bt<MODE_PLAIN><<<dim3(4, 16, 16), 256, 0, stream>>>(
        C_, Q_, S, nullptr, LQ, DIM,
        (long)LC * DIM, (long)LQ * DIM, (long)LC * LQ);

    // 4. masked softmax over q (in place)
    softmax_rows<<<MC, 256, 0, stream>>>(S, Cmask, Qmask);

    // 5. attn[b] = S[b] @ Q[b]   (B-operand = Qt, batched)
    gemm_bt<MODE_PLAIN><<<dim3(4, 16, 16), 256, 0, stream>>>(
        S, Qt, attn, nullptr, DIM, LQ,
        (long)LC * LQ, (long)DIM * LQ, (long)LC * DIM);

    // 6. cat8 = [C | attn | attn-C | attn*C] (fp8)
    build_cat<<<8192, 256, 0, stream>>>(Cb, attn, cat8);

    // 7+8 fused MX-fp8 dual GEMM + activations + gate blend + Cmask (fp32 out)
    gemm_dual_fp8<<<dim3(16, 256, 1), 256, 0, stream>>>(
        cat8, Wf8, Wg8, out, bfp, bgp, cat8, Cmask);
}

// Round 4
// 938.518 us; speedup vs baseline: 5.9161x; 1.0893x over previous
//
#include <hip/hip_runtime.h>
#include <hip/hip_bf16.h>
#include <math.h>

using bf16 = __hip_bfloat16;
typedef __attribute__((ext_vector_type(8))) short s16x8;
typedef __attribute__((ext_vector_type(4))) float f32x4;
typedef __attribute__((ext_vector_type(8))) int i32x8;
typedef __attribute__((ext_vector_type(4))) int i32x4;

#define NEG_INF_F (-1e30f)

// ---------- constants for this problem ----------
static constexpr int BATCH = 16;
static constexpr int LC = 2048;
static constexpr int LQ = 512;
static constexpr int DIM = 512;
static constexpr int FEAT = 2048;          // 4*DIM
static constexpr int MC = BATCH * LC;      // 32768
static constexpr int MQ = BATCH * LQ;      // 8192

__device__ __forceinline__ float bfs2f(short s) {
    union { float f; unsigned u; } x;
    x.u = ((unsigned)(unsigned short)s) << 16;
    return x.f;
}
__device__ __forceinline__ short f2bfs(float f) {
    bf16 h = __float2bfloat16(f);
    short s; __builtin_memcpy(&s, &h, 2);
    return s;
}
// OCP e4m3 byte -> float (decoder, epilogue only)
__device__ __forceinline__ float fp8_to_f(unsigned b) {
    const unsigned s = b >> 7, e = (b >> 3) & 15, m = b & 7;
    const int ee = e ? (int)e : 1;
    const int mm = e ? (int)(8 + m) : (int)m;
    union { unsigned u; float f; } sc; sc.u = (unsigned)(ee + 117) << 23; // 2^(ee-10)
    const float v = (float)mm * sc.f;
    return s ? -v : v;
}
// pack 8 floats -> 8 fp8 e4m3 bytes (saturating RNE via HW cvt)
__device__ __forceinline__ uint2 pk8fp8(float a0, float a1, float a2, float a3,
                                        float a4, float a5, float a6, float a7) {
    uint2 r;
    int w0 = __builtin_amdgcn_cvt_pk_fp8_f32(a0, a1, 0, false);
    w0 = __builtin_amdgcn_cvt_pk_fp8_f32(a2, a3, w0, true);
    int w1 = __builtin_amdgcn_cvt_pk_fp8_f32(a4, a5, 0, false);
    w1 = __builtin_amdgcn_cvt_pk_fp8_f32(a6, a7, w1, true);
    r.x = (unsigned)w0; r.y = (unsigned)w1;
    return r;
}

#define GLL(gp, lp) __builtin_amdgcn_global_load_lds( \
    (const __attribute__((address_space(1))) void*)(gp), \
    (__attribute__((address_space(3))) void*)(lp), 16, 0, 0)

// ---------- fp32 -> bf16 convert ----------
__global__ __launch_bounds__(256) void cvt_f32_bf16(const float* __restrict__ in,
                                                    bf16* __restrict__ out, int n) {
    int i = (blockIdx.x * 256 + threadIdx.x) * 4;
    if (i + 3 < n) {
        float4 v = *(const float4*)(in + i);
        ushort4 o;
        o.x = (unsigned short)f2bfs(v.x);
        o.y = (unsigned short)f2bfs(v.y);
        o.z = (unsigned short)f2bfs(v.z);
        o.w = (unsigned short)f2bfs(v.w);
        *(ushort4*)(out + i) = o;
    } else {
        for (int k = i; k < n; k++) out[k] = __float2bfloat16(in[k]);
    }
}

// ---------- fp32 -> fp8 e4m3 with x32 pre-scale (weights; MX scale 2^-5 compensates) ----------
__global__ __launch_bounds__(256) void cvt_f32_fp8_w(const float* __restrict__ in,
                                                     unsigned char* __restrict__ out, int n) {
    int i = (blockIdx.x * 256 + threadIdx.x) * 4;
    if (i >= n) return;
    float4 v = *(const float4*)(in + i);
    int w0 = __builtin_amdgcn_cvt_pk_fp8_f32(v.x * 32.f, v.y * 32.f, 0, false);
    w0 = __builtin_amdgcn_cvt_pk_fp8_f32(v.z * 32.f, v.w * 32.f, w0, true);
    *(int*)(out + i) = w0;
}

// ---------- per-batch transpose: Q (B,LQ,DIM) f32 -> Qt (B,DIM,LQ) bf16 ----------
__global__ __launch_bounds__(256) void transpose_q(const float* __restrict__ Q,
                                                   bf16* __restrict__ Qt) {
    __shared__ float t[32][33];
    const int b = blockIdx.z;
    const int q0 = blockIdx.x * 32, d0 = blockIdx.y * 32;
    const int tx = threadIdx.x, ty = threadIdx.y; // 32 x 8
    const float* Qb = Q + (long)b * LQ * DIM;
    bf16* Qtb = Qt + (long)b * DIM * LQ;
#pragma unroll
    for (int i = 0; i < 32; i += 8)
        t[ty + i][tx] = Qb[(long)(q0 + ty + i) * DIM + d0 + tx];
    __syncthreads();
#pragma unroll
    for (int i = 0; i < 32; i += 8)
        Qtb[(long)(d0 + ty + i) * LQ + q0 + tx] = __float2bfloat16(t[tx][ty + i]);
}

// ---------- generic bf16 MFMA GEMM: Out[M,N] = A[M,K] @ B[N,K]^T ----------
enum { MODE_PLAIN = 0, MODE_BIAS_LRELU = 1 };

template <int MODE>
__global__ __launch_bounds__(256)
void gemm_bt(const bf16* __restrict__ A, const bf16* __restrict__ B,
             void* __restrict__ Out,
             const float* __restrict__ bias,
             int N, int K,
             long strideA, long strideB, long strideO) {
    constexpr int BM = 128, BN = 128, BK = 32;
    __shared__ __align__(16) bf16 As[BM * BK];
    __shared__ __align__(16) bf16 Bs[BN * BK];

    const int z = blockIdx.z;
    const bf16* Ab = A + (long)z * strideA;
    const bf16* Bb = B + (long)z * strideB;

    const int tid = threadIdx.x;
    const int wave = tid >> 6, lane = tid & 63;
    const int wm = (wave >> 1) * 64, wn = (wave & 1) * 64;
    const int lrow = lane & 15, lq = lane >> 4;

    const int bm0 = blockIdx.y * BM;
    const int bn0 = blockIdx.x * BN;

    const int srow = tid >> 2;
    const int scol = (tid & 3) * 8;

    const bf16* ag = Ab + (long)(bm0 + srow) * K + scol;
    const bf16* bg = Bb + (long)(bn0 + srow) * K + scol;
    bf16* asl = &As[srow * BK + scol];   // byte offset = tid*16: contiguous in lane order
    bf16* bsl = &Bs[srow * BK + scol];
    const long skip64 = (long)64 * K;

    f32x4 acc[4][4];
#pragma unroll
    for (int i = 0; i < 4; i++)
#pragma unroll
        for (int j = 0; j < 4; j++) acc[i][j] = (f32x4){0.f, 0.f, 0.f, 0.f};

    for (int k0 = 0; k0 < K; k0 += BK) {
        GLL(ag, asl);
        GLL(ag + skip64, asl + 64 * BK);
        GLL(bg, bsl);
        GLL(bg + skip64, bsl + 64 * BK);
        ag += BK; bg += BK;
        __syncthreads();

        s16x8 af[4], bfv[4];
#pragma unroll
        for (int f = 0; f < 4; f++)
            af[f] = *(const s16x8*)&As[(wm + f * 16 + lrow) * BK + lq * 8];
#pragma unroll
        for (int f = 0; f < 4; f++)
            bfv[f] = *(const s16x8*)&Bs[(wn + f * 16 + lrow) * BK + lq * 8];

#pragma unroll
        for (int i = 0; i < 4; i++)
#pragma unroll
            for (int j = 0; j < 4; j++)
                acc[i][j] = __builtin_amdgcn_mfma_f32_16x16x32_bf16(af[i], bfv[j], acc[i][j], 0, 0, 0);
        __syncthreads();
    }

    // epilogue: C/D layout col=lane&15, row=(lane>>4)*4+reg  [m89/m91-verified]
#pragma unroll
    for (int i = 0; i < 4; i++) {
#pragma unroll
        for (int j = 0; j < 4; j++) {
            const int n = bn0 + wn + j * 16 + lrow;
            const float bn_bias = (MODE == MODE_PLAIN) ? 0.f : bias[n];
#pragma unroll
            for (int r = 0; r < 4; r++) {
                const int m = bm0 + wm + i * 16 + lq * 4 + r;
                const long off = (long)z * strideO + (long)m * N + n;
                float v = acc[i][j][r];
                if (MODE == MODE_PLAIN) {
                    ((bf16*)Out)[off] = __float2bfloat16(v);
                } else { // MODE_BIAS_LRELU
                    v += bn_bias;
                    v = v > 0.f ? v : 0.01f * v;
                    ((bf16*)Out)[off] = __float2bfloat16(v);
                }
            }
        }
    }
}

// ---------- fused dual GEMM, MX-fp8 K=128, BN=64 + double buffer @ 2 blocks/CU ----------
// fuse = tanh(cat@Wf^T+bf), gate = sigm(cat@Wg^T+bg),
// out = Cmask ? g*fuse+(1-g)*cat : -1e30
// A = cat fp8 (scale 2^0, byte 127); B = weights pre-scaled x32 fp8 (MX scale 2^-5, byte 122).
//
// Ladder evidence: r0 single-buf 48K @2blk/CU = 433us (cross-block TLP hides staging);
// r3 dbuf 96K @1blk/CU = 561us (intra-block overlap < lost inter-block overlap);
// r1/r2 spilled (8-wave reg cap / relaxed bounds+unroll). This version gets BOTH
// ingredients: BN 128->64 halves per-buffer LDS (A 16K|Bf 8K|Bg 8K = 32K; dbuf 64K
// -> 2 blocks/CU) AND halves acc to 64 regs (accf[4][2]+accg[4][2]) -> ~195 unified
// regs, real headroom under launch_bounds(256,2). Allocator-safe loop form kept from
// r3: hard-coded buffer bases, 2 tiles/iter, unroll(disable).
// Per phase: STAGE(other buf, t+1) -> compute this buf -> __syncthreads (only vmcnt
// drain, a full compute-phase after issue; sibling block covers the residual).
// A-tile logical re-reads double (32 bn-blocks/stripe) but cat8=64MB is L3-resident.
// LDS tiles: 16B chunks XOR-swizzled: chunk c of row m at pos c^(m&7) — keeps
// global_load_lds lane-contiguous AND makes fragment ds_reads 2-way-only = free.
__global__ __launch_bounds__(256, 2)
void gemm_dual_fp8(const unsigned char* __restrict__ A8,
                   const unsigned char* __restrict__ Bf8,
                   const unsigned char* __restrict__ Bg8,
                   float* __restrict__ Out,
                   const float* __restrict__ biasf, const float* __restrict__ biasg,
                   const unsigned char* __restrict__ cat8,
                   const int* __restrict__ cmask) {
    constexpr int BM = 128, BN = 64;
    constexpr int N = FEAT, K = FEAT;   // K in bytes per row (fp8)
    constexpr int BUF = 32768;          // per buffer: A 16K | Bf 8K | Bg 8K
    __shared__ __align__(16) char lds[2 * BUF];

    const int tid = threadIdx.x;
    const int wave = tid >> 6, lane = tid & 63;
    const int wm = (wave >> 1) * 64;    // 0,0,64,64
    const int wn = (wave & 1) * 32;     // 0,32
    const int lrow = lane & 15, lq = lane >> 4;

    const int bm0 = blockIdx.y * BM;
    const int bn0 = blockIdx.x * BN;

    // ---- staging: thread t writes LDS chunk at byte tid*16 of a 4KB round (32 rows);
    // that chunk holds global row r0(+32r), k-bytes (p ^ (r0&7))*16 .. +16 ----
    const int p = tid & 7, r0 = tid >> 3;        // r0: 0..31
    const int xo = (p ^ (r0 & 7)) * 16;
    const long Kl = K;
    const unsigned char* agp = A8 + (long)(bm0 + r0) * Kl + xo;
    const unsigned char* bfgp = Bf8 + (long)(bn0 + r0) * Kl + xo;
    const unsigned char* bggp = Bg8 + (long)(bn0 + r0) * Kl + xo;
    const long rowskip = (long)32 * Kl;

#define STAGE8(bufbase, koff) do {                                      \
        char* _ab = (bufbase);                                          \
        GLL(agp + (koff), _ab + tid * 16);                              \
        GLL(agp + (koff) + rowskip, _ab + 4096 + tid * 16);             \
        GLL(agp + (koff) + 2 * rowskip, _ab + 8192 + tid * 16);         \
        GLL(agp + (koff) + 3 * rowskip, _ab + 12288 + tid * 16);        \
        GLL(bfgp + (koff), _ab + 16384 + tid * 16);                     \
        GLL(bfgp + (koff) + rowskip, _ab + 20480 + tid * 16);           \
        GLL(bggp + (koff), _ab + 24576 + tid * 16);                     \
        GLL(bggp + (koff) + rowskip, _ab + 28672 + tid * 16);           \
    } while (0)

    // ---- fragment ds_read offsets (loop-invariant): frag (row, kq=lq) half h
    // stored at row*128 + ((lq*2+h)^(row&7))*16; note off(h=1) = off(h=0) ^ 16 ----
    int offA[4], offB[2];
#pragma unroll
    for (int f = 0; f < 4; f++) {
        const int ra = wm + f * 16 + lrow;       // 0..127
        offA[f] = ra * 128 + (((lq * 2) ^ (ra & 7)) * 16);
    }
#pragma unroll
    for (int j = 0; j < 2; j++) {
        const int rb = wn + j * 16 + lrow;       // 0..63
        offB[j] = rb * 128 + (((lq * 2) ^ (rb & 7)) * 16);
    }

    f32x4 accf[4][2], accg[4][2];
#pragma unroll
    for (int i = 0; i < 4; i++)
#pragma unroll
        for (int j = 0; j < 2; j++) {
            accf[i][j] = (f32x4){0.f, 0.f, 0.f, 0.f};
            accg[i][j] = (f32x4){0.f, 0.f, 0.f, 0.f};
        }

    // one K-tile compute on a compile-time-constant buffer base
#define COMPUTE(bufbase) do {                                               \
        const char* Asb = (bufbase);                                        \
        const char* Bfb = (bufbase) + 16384;                                \
        const char* Bgb = (bufbase) + 24576;                                \
        i32x8 af[4];                                                        \
        _Pragma("unroll")                                                   \
        for (int f = 0; f < 4; f++) {                                       \
            const i32x4 lo = *(const i32x4*)(Asb + offA[f]);                \
            const i32x4 hi = *(const i32x4*)(Asb + (offA[f] ^ 16));         \
            af[f][0] = lo[0]; af[f][1] = lo[1]; af[f][2] = lo[2];           \
            af[f][3] = lo[3]; af[f][4] = hi[0]; af[f][5] = hi[1];           \
            af[f][6] = hi[2]; af[f][7] = hi[3];                             \
        }                                                                   \
        _Pragma("unroll")                                                   \
        for (int j = 0; j < 2; j++) {                                       \
            i32x8 bfj, bgj;                                                 \
            {                                                               \
                const i32x4 lo = *(const i32x4*)(Bfb + offB[j]);            \
                const i32x4 hi = *(const i32x4*)(Bfb + (offB[j] ^ 16));     \
                bfj[0] = lo[0]; bfj[1] = lo[1]; bfj[2] = lo[2];             \
                bfj[3] = lo[3]; bfj[4] = hi[0]; bfj[5] = hi[1];             \
                bfj[6] = hi[2]; bfj[7] = hi[3];                             \
            }                                                               \
            {                                                               \
                const i32x4 lo = *(const i32x4*)(Bgb + offB[j]);            \
                const i32x4 hi = *(const i32x4*)(Bgb + (offB[j] ^ 16));     \
                bgj[0] = lo[0]; bgj[1] = lo[1]; bgj[2] = lo[2];             \
                bgj[3] = lo[3]; bgj[4] = hi[0]; bgj[5] = hi[1];             \
                bgj[6] = hi[2]; bgj[7] = hi[3];                             \
            }                                                               \
            _Pragma("unroll")                                               \
            for (int i = 0; i < 4; i++)                                     \
                accf[i][j] = __builtin_amdgcn_mfma_scale_f32_16x16x128_f8f6f4( \
                    af[i], bfj, accf[i][j], 0, 0, 0, 127, 0, 122);          \
            _Pragma("unroll")                                               \
            for (int i = 0; i < 4; i++)                                     \
                accg[i][j] = __builtin_amdgcn_mfma_scale_f32_16x16x128_f8f6f4( \
                    af[i], bgj, accg[i][j], 0, 0, 0, 127, 0, 122);          \
        }                                                                   \
    } while (0)

    // prologue: stage tile 0 into buf0; barrier drains vmcnt(0)
    STAGE8(lds, 0);
    __syncthreads();

    constexpr int NT = K / 128;   // 16 K-tiles, 2 per iteration
#pragma clang loop unroll(disable)
    for (int kt = 0; kt < NT; kt += 2) {
        // phase A: prefetch tile kt+1 into buf1 (kt+1 <= 15 always), compute buf0
        STAGE8(lds + BUF, (long)(kt + 1) * 128);
        COMPUTE(lds);
        __syncthreads();   // drains vmcnt: buf1 resident; buf0 free to overwrite
        // phase B: prefetch tile kt+2 into buf0, compute buf1
        if (kt + 2 < NT) STAGE8(lds, (long)(kt + 2) * 128);
        COMPUTE(lds + BUF);
        __syncthreads();   // drains vmcnt: buf0 resident; buf1 free to overwrite
    }
#undef STAGE8
#undef COMPUTE

    // epilogue: C/D layout col=lane&15, row=(lane>>4)*4+reg (shape-determined)
#pragma unroll
    for (int j = 0; j < 2; j++) {
        const int n = bn0 + wn + j * 16 + lrow;
        const float bfb = biasf[n];
        const float bgb = biasg[n];
#pragma unroll
        for (int i = 0; i < 4; i++) {
#pragma unroll
            for (int r = 0; r < 4; r++) {
                const int m = bm0 + wm + i * 16 + lq * 4 + r;
                const long off = (long)m * N + n;
                const float vf = accf[i][j][r] + bfb;
                const float vg = accg[i][j][r] + bgb;
                const float e = __expf(2.0f * fabsf(vf));
                const float th = copysignf(1.0f - 2.0f / (e + 1.0f), vf);
                const float g = 1.0f / (1.0f + __expf(-vg));
                const float c = fp8_to_f(cat8[off]);
                Out[off] = cmask[m] ? (g * th + (1.0f - g) * c) : NEG_INF_F;
            }
        }
    }
}

// ---------- masked row softmax over LQ=512, in place on bf16 S ----------
// wave-per-row: 4 waves/block handle 4 rows; lane l owns 8 contiguous elems
// (one s16x8 load). shfl_xor reductions only — no LDS, no __syncthreads.
__global__ __launch_bounds__(256) void softmax_rows(bf16* __restrict__ S,
                                                    const int* __restrict__ Cmask,
                                                    const int* __restrict__ Qmask) {
    const int row = blockIdx.x * 4 + (threadIdx.x >> 6);   // 0 .. B*LC-1
    const int lane = threadIdx.x & 63;
    const int b = row >> 11;            // LC = 2048
    bf16* srow = S + (long)row * LQ;
    short* sp = (short*)srow + lane * 8;

    if (Cmask[row] == 0) {
        const short u = f2bfs(1.0f / 512.0f);
        s16x8 uv;
#pragma unroll
        for (int i = 0; i < 8; i++) uv[i] = u;
        *(s16x8*)sp = uv;
        return;
    }

    const int* qm = Qmask + b * LQ + lane * 8;
    const int4 m0 = *(const int4*)(qm);
    const int4 m1 = *(const int4*)(qm + 4);
    const int msk[8] = {m0.x, m0.y, m0.z, m0.w, m1.x, m1.y, m1.z, m1.w};
    const s16x8 sv = *(const s16x8*)sp;

    float v[8];
    float mx = -3e38f;
#pragma unroll
    for (int i = 0; i < 8; i++) {
        v[i] = msk[i] ? bfs2f(sv[i]) : -3e38f;
        mx = fmaxf(mx, v[i]);
    }
#pragma unroll
    for (int o = 32; o > 0; o >>= 1) mx = fmaxf(mx, __shfl_xor(mx, o, 64));

    float e[8];
    float s = 0.f;
#pragma unroll
    for (int i = 0; i < 8; i++) {
        e[i] = msk[i] ? __expf(v[i] - mx) : 0.f;
        s += e[i];
    }
#pragma unroll
    for (int o = 32; o > 0; o >>= 1) s += __shfl_xor(s, o, 64);

    s16x8 ov;
    if (!(s > 0.f)) {
        const short u = f2bfs(1.0f / 512.0f);
#pragma unroll
        for (int i = 0; i < 8; i++) ov[i] = u;
    } else {
        const float inv = 1.0f / s;
#pragma unroll
        for (int i = 0; i < 8; i++) ov[i] = f2bfs(e[i] * inv);
    }
    *(s16x8*)sp = ov;
}

// ---------- build cat = [C | attn | attn-C | attn*C] as fp8 e4m3 ----------
__global__ __launch_bounds__(256) void build_cat(const bf16* __restrict__ Cb,
                                                 const bf16* __restrict__ attn,
                                                 unsigned char* __restrict__ cat8) {
    const long t = (long)blockIdx.x * 256 + threadIdx.x;
    const int m = (int)(t >> 6);
    const int c = (int)(t & 63) << 3;
    const s16x8 cv = *(const s16x8*)((const short*)Cb + (long)m * DIM + c);
    const s16x8 av = *(const s16x8*)((const short*)attn + (long)m * DIM + c);
    float cf[8], af_[8];
#pragma unroll
    for (int i = 0; i < 8; i++) { cf[i] = bfs2f(cv[i]); af_[i] = bfs2f(av[i]); }
    unsigned char* rowp = cat8 + (long)m * FEAT + c;
    *(uint2*)(rowp) = pk8fp8(cf[0], cf[1], cf[2], cf[3], cf[4], cf[5], cf[6], cf[7]);
    *(uint2*)(rowp + 512) = pk8fp8(af_[0], af_[1], af_[2], af_[3], af_[4], af_[5], af_[6], af_[7]);
    *(uint2*)(rowp + 1024) = pk8fp8(af_[0] - cf[0], af_[1] - cf[1], af_[2] - cf[2], af_[3] - cf[3],
                                    af_[4] - cf[4], af_[5] - cf[5], af_[6] - cf[6], af_[7] - cf[7]);
    *(uint2*)(rowp + 1536) = pk8fp8(af_[0] * cf[0], af_[1] * cf[1], af_[2] * cf[2], af_[3] * cf[3],
                                    af_[4] * cf[4], af_[5] * cf[5], af_[6] * cf[6], af_[7] * cf[7]);
}

extern "C" void kernel_launch(void* const* d_in, const int* in_sizes, int n_in,
                              void* d_out, int out_size, void* d_ws, size_t ws_size,
                              hipStream_t stream) {
    (void)in_sizes; (void)n_in; (void)out_size; (void)ws_size;
    const float* C = (const float*)d_in[0];
    const float* Q = (const float*)d_in[1];
    const int* Cmask = (const int*)d_in[2];
    const int* Qmask = (const int*)d_in[3];
    const float* W1 = (const float*)d_in[4];
    const float* b1 = (const float*)d_in[5];
    const float* Wf = (const float*)d_in[6];
    const float* bfp = (const float*)d_in[7];
    const float* Wg = (const float*)d_in[8];
    const float* bgp = (const float*)d_in[9];
    float* out = (float*)d_out;

    // ---- workspace layout (bytes). cat8 overlaps the dead early temps
    // (W1b/Qb/Qt/C_/Q_/S are all last read before build_cat writes cat8). ----
    char* ws = (char*)d_ws;
    unsigned char* cat8 = (unsigned char*)(ws + 0);     //  67,108,864
    bf16* W1b  = (bf16*)(ws + 0);                       //     524,288
    bf16* Qb   = (bf16*)(ws + 524288);                  //   8,388,608
    bf16* Qt   = (bf16*)(ws + 8912896);                 //   8,388,608
    bf16* C_   = (bf16*)(ws + 17301504);                //  33,554,432
    bf16* Q_   = (bf16*)(ws + 50855936);                //   8,388,608
    bf16* S    = (bf16*)(ws + 59244544);                //  33,554,432 (dead before cat8 write)
    bf16* Cb   = (bf16*)(ws + 134217728);               //  33,554,432
    bf16* attn = (bf16*)(ws + 167772160);               //  33,554,432
    unsigned char* Wf8 = (unsigned char*)(ws + 201326592); // 4,194,304
    unsigned char* Wg8 = (unsigned char*)(ws + 205520896); // 4,194,304 (end ~209.7MB)

    // 1. dtype conversions
    cvt_f32_bf16<<<256, 256, 0, stream>>>(W1, W1b, DIM * DIM);
    cvt_f32_fp8_w<<<4096, 256, 0, stream>>>(Wf, Wf8, FEAT * FEAT);
    cvt_f32_fp8_w<<<4096, 256, 0, stream>>>(Wg, Wg8, FEAT * FEAT);
    cvt_f32_bf16<<<16384, 256, 0, stream>>>(C, Cb, MC * DIM);
    cvt_f32_bf16<<<4096, 256, 0, stream>>>(Q, Qb, MQ * DIM);
    transpose_q<<<dim3(16, 16, 16), dim3(32, 8), 0, stream>>>(Q, Qt);

    // 2. C_ = lrelu(C @ W1^T + b1), Q_ = lrelu(Q @ W1^T + b1)  (bf16 out)
    gemm_bt<MODE_BIAS_LRELU><<<dim3(4, 256, 1), 256, 0, stream>>>(
        Cb, W1b, C_, b1, DIM, DIM, 0, 0, 0);
    gemm_bt<MODE_BIAS_LRELU><<<dim3(4, 64, 1), 256, 0, stream>>>(
        Qb, W1b, Q_, b1, DIM, DIM, 0, 0, 0);

    // 3. S[b] = C_[b] @ Q_[b]^T  (batched, bf16 logits)
    gemm_bt<MODE_PLAIN><<<dim3(4, 16, 16), 256, 0, stream>>>(
        C_, Q_, S, nullptr, LQ, DIM,
        (long)LC * DIM, (long)LQ * DIM, (long)LC * LQ);

    // 4. masked softmax over q (in place, wave per row)
    softmax_rows<<<MC / 4, 256, 0, stream>>>(S, Cmask, Qmask);

    // 5. attn[b] = S[b] @ Q[b]   (B-operand = Qt, batched)
    gemm_bt<MODE_PLAIN><<<dim3(4, 16, 16), 256, 0, stream>>>(
        S, Qt, attn, nullptr, DIM, LQ,
        (long)LC * LQ, (long)DIM * LQ, (long)LC * DIM);

    // 6. cat8 = [C | attn | attn-C | attn*C] (fp8)
    build_cat<<<8192, 256, 0, stream>>>(Cb, attn, cat8);

    // 7+8 fused MX-fp8 dual GEMM + activations + gate blend + Cmask (fp32 out)
    gemm_dual_fp8<<<dim3(32, 256, 1), 256, 0, stream>>>(
        cat8, Wf8, Wg8, out, bfp, bgp, cat8, Cmask);
}

// Round 5
// 733.190 us; speedup vs baseline: 7.5729x; 1.2800x over previous
//
#include <hip/hip_runtime.h>
#include <hip/hip_bf16.h>
#include <math.h>

using bf16 = __hip_bfloat16;
typedef __attribute__((ext_vector_type(8))) short s16x8;
typedef __attribute__((ext_vector_type(4))) float f32x4;
typedef __attribute__((ext_vector_type(8))) int i32x8;
typedef __attribute__((ext_vector_type(4))) int i32x4;

#define NEG_INF_F (-1e30f)

// ---------- constants for this problem ----------
static constexpr int BATCH = 16;
static constexpr int LC = 2048;
static constexpr int LQ = 512;
static constexpr int DIM = 512;
static constexpr int FEAT = 2048;          // 4*DIM
static constexpr int MC = BATCH * LC;      // 32768
static constexpr int MQ = BATCH * LQ;      // 8192

__device__ __forceinline__ float bfs2f(short s) {
    union { float f; unsigned u; } x;
    x.u = ((unsigned)(unsigned short)s) << 16;
    return x.f;
}
__device__ __forceinline__ short f2bfs(float f) {
    bf16 h = __float2bfloat16(f);
    short s; __builtin_memcpy(&s, &h, 2);
    return s;
}
// OCP e4m3 byte -> float (decoder, epilogue only)
__device__ __forceinline__ float fp8_to_f(unsigned b) {
    const unsigned s = b >> 7, e = (b >> 3) & 15, m = b & 7;
    const int ee = e ? (int)e : 1;
    const int mm = e ? (int)(8 + m) : (int)m;
    union { unsigned u; float f; } sc; sc.u = (unsigned)(ee + 117) << 23; // 2^(ee-10)
    const float v = (float)mm * sc.f;
    return s ? -v : v;
}
// pack 8 floats -> 8 fp8 e4m3 bytes (saturating RNE via HW cvt)
__device__ __forceinline__ uint2 pk8fp8(float a0, float a1, float a2, float a3,
                                        float a4, float a5, float a6, float a7) {
    uint2 r;
    int w0 = __builtin_amdgcn_cvt_pk_fp8_f32(a0, a1, 0, false);
    w0 = __builtin_amdgcn_cvt_pk_fp8_f32(a2, a3, w0, true);
    int w1 = __builtin_amdgcn_cvt_pk_fp8_f32(a4, a5, 0, false);
    w1 = __builtin_amdgcn_cvt_pk_fp8_f32(a6, a7, w1, true);
    r.x = (unsigned)w0; r.y = (unsigned)w1;
    return r;
}

#define GLL(gp, lp) __builtin_amdgcn_global_load_lds( \
    (const __attribute__((address_space(1))) void*)(gp), \
    (__attribute__((address_space(3))) void*)(lp), 16, 0, 0)

// ---------- fp32 -> bf16 convert ----------
__global__ __launch_bounds__(256) void cvt_f32_bf16(const float* __restrict__ in,
                                                    bf16* __restrict__ out, int n) {
    int i = (blockIdx.x * 256 + threadIdx.x) * 4;
    if (i + 3 < n) {
        float4 v = *(const float4*)(in + i);
        ushort4 o;
        o.x = (unsigned short)f2bfs(v.x);
        o.y = (unsigned short)f2bfs(v.y);
        o.z = (unsigned short)f2bfs(v.z);
        o.w = (unsigned short)f2bfs(v.w);
        *(ushort4*)(out + i) = o;
    } else {
        for (int k = i; k < n; k++) out[k] = __float2bfloat16(in[k]);
    }
}

// ---------- fp32 -> fp8 e4m3 with x32 pre-scale (weights; MX scale 2^-5 compensates) ----------
__global__ __launch_bounds__(256) void cvt_f32_fp8_w(const float* __restrict__ in,
                                                     unsigned char* __restrict__ out, int n) {
    int i = (blockIdx.x * 256 + threadIdx.x) * 4;
    if (i >= n) return;
    float4 v = *(const float4*)(in + i);
    int w0 = __builtin_amdgcn_cvt_pk_fp8_f32(v.x * 32.f, v.y * 32.f, 0, false);
    w0 = __builtin_amdgcn_cvt_pk_fp8_f32(v.z * 32.f, v.w * 32.f, w0, true);
    *(int*)(out + i) = w0;
}

// ---------- per-batch transpose: Q (B,LQ,DIM) f32 -> Qt (B,DIM,LQ) bf16 ----------
__global__ __launch_bounds__(256) void transpose_q(const float* __restrict__ Q,
                                                   bf16* __restrict__ Qt) {
    __shared__ float t[32][33];
    const int b = blockIdx.z;
    const int q0 = blockIdx.x * 32, d0 = blockIdx.y * 32;
    const int tx = threadIdx.x, ty = threadIdx.y; // 32 x 8
    const float* Qb = Q + (long)b * LQ * DIM;
    bf16* Qtb = Qt + (long)b * DIM * LQ;
#pragma unroll
    for (int i = 0; i < 32; i += 8)
        t[ty + i][tx] = Qb[(long)(q0 + ty + i) * DIM + d0 + tx];
    __syncthreads();
#pragma unroll
    for (int i = 0; i < 32; i += 8)
        Qtb[(long)(d0 + ty + i) * LQ + q0 + tx] = __float2bfloat16(t[tx][ty + i]);
}

// ---------- mask compaction: idx[j] = original row of j-th unmasked row ----------
// 3 tiny deterministic kernels (no atomics): per-batch count -> serial scan of 16
// -> per-batch compaction with wave/LDS prefix scan. offs[16] = Mprime (total).
__global__ __launch_bounds__(256) void mask_count(const int* __restrict__ cm,
                                                  int* __restrict__ cnt) {
    const int b = blockIdx.x;
    const int* p = cm + b * LC;
    int s = 0;
    for (int i = threadIdx.x; i < LC; i += 256) s += p[i] ? 1 : 0;
#pragma unroll
    for (int o = 32; o > 0; o >>= 1) s += __shfl_down(s, o, 64);
    __shared__ int red[4];
    if ((threadIdx.x & 63) == 0) red[threadIdx.x >> 6] = s;
    __syncthreads();
    if (threadIdx.x == 0) cnt[b] = red[0] + red[1] + red[2] + red[3];
}
__global__ void mask_scan(const int* __restrict__ cnt, int* __restrict__ off) {
    if (threadIdx.x == 0) {
        int a = 0;
        for (int b = 0; b < BATCH; b++) { off[b] = a; a += cnt[b]; }
        off[BATCH] = a;   // Mprime
    }
}
__global__ __launch_bounds__(256) void mask_compact(const int* __restrict__ cm,
                                                    const int* __restrict__ off,
                                                    int* __restrict__ idx) {
    const int b = blockIdx.x;
    const int tid = threadIdx.x;
    const int lane = tid & 63, wv = tid >> 6;
    const int* p = cm + b * LC + tid * 8;
    int f[8], ls = 0;
#pragma unroll
    for (int i = 0; i < 8; i++) { f[i] = p[i] ? 1 : 0; ls += f[i]; }
    int inc = ls;   // inclusive wave scan of per-thread sums
#pragma unroll
    for (int o = 1; o < 64; o <<= 1) {
        int y = __shfl_up(inc, o, 64);
        if (lane >= o) inc += y;
    }
    __shared__ int wsum[4];
    if (lane == 63) wsum[wv] = inc;
    __syncthreads();
    int base = off[b];
    for (int w = 0; w < wv; w++) base += wsum[w];
    int ex = base + inc - ls;             // global exclusive prefix
    const int orig = b * LC + tid * 8;
    for (int i = 0; i < 8; i++)
        if (f[i]) idx[ex++] = orig + i;
}

// ---------- fill masked output rows with exactly -1e30 ----------
__global__ __launch_bounds__(256) void fill_masked(float* __restrict__ out,
                                                   const int* __restrict__ cm) {
    const float4 v = make_float4(NEG_INF_F, NEG_INF_F, NEG_INF_F, NEG_INF_F);
    const long total = (long)MC * (FEAT / 4);           // float4 elements
    const long stride = (long)gridDim.x * 256;
    for (long p = (long)blockIdx.x * 256 + threadIdx.x; p < total; p += stride) {
        const int row = (int)(p >> 9);                  // FEAT/4 = 512 f4 per row
        if (cm[row] == 0) ((float4*)out)[p] = v;
    }
}

// ---------- generic bf16 MFMA GEMM: Out[M,N] = A[M,K] @ B[N,K]^T ----------
enum { MODE_PLAIN = 0, MODE_BIAS_LRELU = 1 };

template <int MODE>
__global__ __launch_bounds__(256)
void gemm_bt(const bf16* __restrict__ A, const bf16* __restrict__ B,
             void* __restrict__ Out,
             const float* __restrict__ bias,
             int N, int K,
             long strideA, long strideB, long strideO) {
    constexpr int BM = 128, BN = 128, BK = 32;
    __shared__ __align__(16) bf16 As[BM * BK];
    __shared__ __align__(16) bf16 Bs[BN * BK];

    const int z = blockIdx.z;
    const bf16* Ab = A + (long)z * strideA;
    const bf16* Bb = B + (long)z * strideB;

    const int tid = threadIdx.x;
    const int wave = tid >> 6, lane = tid & 63;
    const int wm = (wave >> 1) * 64, wn = (wave & 1) * 64;
    const int lrow = lane & 15, lq = lane >> 4;

    const int bm0 = blockIdx.y * BM;
    const int bn0 = blockIdx.x * BN;

    const int srow = tid >> 2;
    const int scol = (tid & 3) * 8;

    const bf16* ag = Ab + (long)(bm0 + srow) * K + scol;
    const bf16* bg = Bb + (long)(bn0 + srow) * K + scol;
    bf16* asl = &As[srow * BK + scol];   // byte offset = tid*16: contiguous in lane order
    bf16* bsl = &Bs[srow * BK + scol];
    const long skip64 = (long)64 * K;

    f32x4 acc[4][4];
#pragma unroll
    for (int i = 0; i < 4; i++)
#pragma unroll
        for (int j = 0; j < 4; j++) acc[i][j] = (f32x4){0.f, 0.f, 0.f, 0.f};

    for (int k0 = 0; k0 < K; k0 += BK) {
        GLL(ag, asl);
        GLL(ag + skip64, asl + 64 * BK);
        GLL(bg, bsl);
        GLL(bg + skip64, bsl + 64 * BK);
        ag += BK; bg += BK;
        __syncthreads();

        s16x8 af[4], bfv[4];
#pragma unroll
        for (int f = 0; f < 4; f++)
            af[f] = *(const s16x8*)&As[(wm + f * 16 + lrow) * BK + lq * 8];
#pragma unroll
        for (int f = 0; f < 4; f++)
            bfv[f] = *(const s16x8*)&Bs[(wn + f * 16 + lrow) * BK + lq * 8];

#pragma unroll
        for (int i = 0; i < 4; i++)
#pragma unroll
            for (int j = 0; j < 4; j++)
                acc[i][j] = __builtin_amdgcn_mfma_f32_16x16x32_bf16(af[i], bfv[j], acc[i][j], 0, 0, 0);
        __syncthreads();
    }

    // epilogue: C/D layout col=lane&15, row=(lane>>4)*4+reg  [m89/m91-verified]
#pragma unroll
    for (int i = 0; i < 4; i++) {
#pragma unroll
        for (int j = 0; j < 4; j++) {
            const int n = bn0 + wn + j * 16 + lrow;
            const float bn_bias = (MODE == MODE_PLAIN) ? 0.f : bias[n];
#pragma unroll
            for (int r = 0; r < 4; r++) {
                const int m = bm0 + wm + i * 16 + lq * 4 + r;
                const long off = (long)z * strideO + (long)m * N + n;
                float v = acc[i][j][r];
                if (MODE == MODE_PLAIN) {
                    ((bf16*)Out)[off] = __float2bfloat16(v);
                } else { // MODE_BIAS_LRELU
                    v += bn_bias;
                    v = v > 0.f ? v : 0.01f * v;
                    ((bf16*)Out)[off] = __float2bfloat16(v);
                }
            }
        }
    }
}

// ---------- fused dual GEMM, MX-fp8 K=128, COMPACTED rows ----------
// fuse = tanh(cat@Wf^T+bf), gate = sigm(cat@Wg^T+bg), out[idx[m]] = g*fuse+(1-g)*cat
// A8 = COMPACTED cat fp8 (rows 0..Mprime-1 are the unmasked original rows, via idx).
// K-loop/staging/LDS layout byte-identical to the verified 433us round-0 kernel
// (single 48KB buffer, 2 blocks/CU; rounds 1-4 showed every pipelined variant is
// either register-spilled or occupancy-starved). The win here is WORK DELETION:
// ~50% of rows have Cmask=0 and their output is overwritten by -1e30 in the
// reference, so we only compute unmasked rows (blocks past Mprime exit at entry;
// tail-block rows >= Mprime compute on garbage in-bounds fp8 and are not stored).
// B = weights pre-scaled x32 fp8 (MX scale 2^-5, byte 122); A scale 2^0 (byte 127).
// LDS tiles: 16B chunks XOR-swizzled: chunk c of row m at pos c^(m&7).
__global__ __launch_bounds__(256, 2)
void gemm_dual_fp8(const unsigned char* __restrict__ A8,
                   const unsigned char* __restrict__ Bf8,
                   const unsigned char* __restrict__ Bg8,
                   float* __restrict__ Out,
                   const float* __restrict__ biasf, const float* __restrict__ biasg,
                   const int* __restrict__ idx,
                   const int* __restrict__ offs) {
    constexpr int BM = 128, BN = 128;
    constexpr int N = FEAT, K = FEAT;   // K in bytes per row (fp8)
    __shared__ __align__(16) char As[BM * 128];
    __shared__ __align__(16) char Bfs[BN * 128];
    __shared__ __align__(16) char Bgs[BN * 128];

    const int Mp = offs[BATCH];
    const int bm0 = blockIdx.y * BM;
    if (bm0 >= Mp) return;               // uniform early-exit: row block fully masked out
    const int bn0 = blockIdx.x * BN;

    const int tid = threadIdx.x;
    const int wave = tid >> 6, lane = tid & 63;
    const int wm = (wave >> 1) * 64, wn = (wave & 1) * 64;
    const int lrow = lane & 15, lq = lane >> 4;

    // ---- staging: thread t writes LDS chunk q=t+256r at byte q*16; that chunk
    // holds global row (r0+32r), k-bytes (p ^ (r0&7))*16 .. +16 ----
    const int p = tid & 7, r0 = tid >> 3;
    const int xo = (p ^ (r0 & 7)) * 16;
    const unsigned char* agp = A8 + (long)(bm0 + r0) * K + xo;
    const unsigned char* bfgp = Bf8 + (long)(bn0 + r0) * K + xo;
    const unsigned char* bggp = Bg8 + (long)(bn0 + r0) * K + xo;
    char* asl = As + tid * 16;
    char* bfl = Bfs + tid * 16;
    char* bgl = Bgs + tid * 16;
    const long rowskip = (long)32 * K;

    // ---- fragment ds_read offsets (loop-invariant): frag (row, kq=lq) halves h=0,1
    // stored at row*128 + ((lq*2+h)^(row&7))*16 ----
    int offA0[4], offA1[4], offB0[4], offB1[4];
#pragma unroll
    for (int f = 0; f < 4; f++) {
        const int ra = wm + f * 16 + lrow;
        offA0[f] = ra * 128 + (((lq * 2 + 0) ^ (ra & 7)) * 16);
        offA1[f] = ra * 128 + (((lq * 2 + 1) ^ (ra & 7)) * 16);
        const int rb = wn + f * 16 + lrow;
        offB0[f] = rb * 128 + (((lq * 2 + 0) ^ (rb & 7)) * 16);
        offB1[f] = rb * 128 + (((lq * 2 + 1) ^ (rb & 7)) * 16);
    }

    f32x4 accf[4][4], accg[4][4];
#pragma unroll
    for (int i = 0; i < 4; i++)
#pragma unroll
        for (int j = 0; j < 4; j++) {
            accf[i][j] = (f32x4){0.f, 0.f, 0.f, 0.f};
            accg[i][j] = (f32x4){0.f, 0.f, 0.f, 0.f};
        }

    for (int k0 = 0; k0 < K; k0 += 128) {
#pragma unroll
        for (int r = 0; r < 4; r++) {
            GLL(agp + (long)r * rowskip, asl + r * 4096);
            GLL(bfgp + (long)r * rowskip, bfl + r * 4096);
            GLL(bggp + (long)r * rowskip, bgl + r * 4096);
        }
        agp += 128; bfgp += 128; bggp += 128;
        __syncthreads();

        i32x8 af[4];
#pragma unroll
        for (int f = 0; f < 4; f++) {
            const i32x4 lo = *(const i32x4*)(As + offA0[f]);
            const i32x4 hi = *(const i32x4*)(As + offA1[f]);
            af[f][0] = lo[0]; af[f][1] = lo[1]; af[f][2] = lo[2]; af[f][3] = lo[3];
            af[f][4] = hi[0]; af[f][5] = hi[1]; af[f][6] = hi[2]; af[f][7] = hi[3];
        }
#pragma unroll
        for (int j = 0; j < 4; j++) {
            i32x8 bfj, bgj;
            {
                const i32x4 lo = *(const i32x4*)(Bfs + offB0[j]);
                const i32x4 hi = *(const i32x4*)(Bfs + offB1[j]);
                bfj[0] = lo[0]; bfj[1] = lo[1]; bfj[2] = lo[2]; bfj[3] = lo[3];
                bfj[4] = hi[0]; bfj[5] = hi[1]; bfj[6] = hi[2]; bfj[7] = hi[3];
            }
            {
                const i32x4 lo = *(const i32x4*)(Bgs + offB0[j]);
                const i32x4 hi = *(const i32x4*)(Bgs + offB1[j]);
                bgj[0] = lo[0]; bgj[1] = lo[1]; bgj[2] = lo[2]; bgj[3] = lo[3];
                bgj[4] = hi[0]; bgj[5] = hi[1]; bgj[6] = hi[2]; bgj[7] = hi[3];
            }
#pragma unroll
            for (int i = 0; i < 4; i++)
                accf[i][j] = __builtin_amdgcn_mfma_scale_f32_16x16x128_f8f6f4(
                    af[i], bfj, accf[i][j], 0, 0, 0, 127, 0, 122);
#pragma unroll
            for (int i = 0; i < 4; i++)
                accg[i][j] = __builtin_amdgcn_mfma_scale_f32_16x16x128_f8f6f4(
                    af[i], bgj, accg[i][j], 0, 0, 0, 127, 0, 122);
        }
        __syncthreads();
    }

    // epilogue: C/D layout col=lane&15, row=(lane>>4)*4+reg; scatter via idx
#pragma unroll
    for (int j = 0; j < 4; j++) {
        const int n = bn0 + wn + j * 16 + lrow;
        const float bfb = biasf[n];
        const float bgb = biasg[n];
#pragma unroll
        for (int i = 0; i < 4; i++) {
#pragma unroll
            for (int r = 0; r < 4; r++) {
                const int m = bm0 + wm + i * 16 + lq * 4 + r;
                if (m < Mp) {
                    const float vf = accf[i][j][r] + bfb;
                    const float vg = accg[i][j][r] + bgb;
                    const float e = __expf(2.0f * fabsf(vf));
                    const float th = copysignf(1.0f - 2.0f / (e + 1.0f), vf);
                    const float g = 1.0f / (1.0f + __expf(-vg));
                    const float c = fp8_to_f(A8[(long)m * N + n]);
                    Out[(long)idx[m] * N + n] = g * th + (1.0f - g) * c;
                }
            }
        }
    }
}

// ---------- masked row softmax over LQ=512, in place on bf16 S ----------
// wave-per-row: 4 waves/block handle 4 rows; lane l owns 8 contiguous elems
// (one s16x8 load). shfl_xor reductions only — no LDS, no __syncthreads.
__global__ __launch_bounds__(256) void softmax_rows(bf16* __restrict__ S,
                                                    const int* __restrict__ Cmask,
                                                    const int* __restrict__ Qmask) {
    const int row = blockIdx.x * 4 + (threadIdx.x >> 6);   // 0 .. B*LC-1
    const int lane = threadIdx.x & 63;
    const int b = row >> 11;            // LC = 2048
    bf16* srow = S + (long)row * LQ;
    short* sp = (short*)srow + lane * 8;

    if (Cmask[row] == 0) {
        const short u = f2bfs(1.0f / 512.0f);
        s16x8 uv;
#pragma unroll
        for (int i = 0; i < 8; i++) uv[i] = u;
        *(s16x8*)sp = uv;
        return;
    }

    const int* qm = Qmask + b * LQ + lane * 8;
    const int4 m0 = *(const int4*)(qm);
    const int4 m1 = *(const int4*)(qm + 4);
    const int msk[8] = {m0.x, m0.y, m0.z, m0.w, m1.x, m1.y, m1.z, m1.w};
    const s16x8 sv = *(const s16x8*)sp;

    float v[8];
    float mx = -3e38f;
#pragma unroll
    for (int i = 0; i < 8; i++) {
        v[i] = msk[i] ? bfs2f(sv[i]) : -3e38f;
        mx = fmaxf(mx, v[i]);
    }
#pragma unroll
    for (int o = 32; o > 0; o >>= 1) mx = fmaxf(mx, __shfl_xor(mx, o, 64));

    float e[8];
    float s = 0.f;
#pragma unroll
    for (int i = 0; i < 8; i++) {
        e[i] = msk[i] ? __expf(v[i] - mx) : 0.f;
        s += e[i];
    }
#pragma unroll
    for (int o = 32; o > 0; o >>= 1) s += __shfl_xor(s, o, 64);

    s16x8 ov;
    if (!(s > 0.f)) {
        const short u = f2bfs(1.0f / 512.0f);
#pragma unroll
        for (int i = 0; i < 8; i++) ov[i] = u;
    } else {
        const float inv = 1.0f / s;
#pragma unroll
        for (int i = 0; i < 8; i++) ov[i] = f2bfs(e[i] * inv);
    }
    *(s16x8*)sp = ov;
}

// ---------- build COMPACTED cat = [C | attn | attn-C | attn*C] as fp8 e4m3 ----------
// compacted row j gathers original row idx[j]; rows >= Mprime skipped.
__global__ __launch_bounds__(256) void build_cat(const bf16* __restrict__ Cb,
                                                 const bf16* __restrict__ attn,
                                                 unsigned char* __restrict__ cat8,
                                                 const int* __restrict__ idx,
                                                 const int* __restrict__ offs) {
    const long t = (long)blockIdx.x * 256 + threadIdx.x;
    const int j = (int)(t >> 6);
    if (j >= offs[BATCH]) return;
    const int m = idx[j];
    const int c = (int)(t & 63) << 3;
    const s16x8 cv = *(const s16x8*)((const short*)Cb + (long)m * DIM + c);
    const s16x8 av = *(const s16x8*)((const short*)attn + (long)m * DIM + c);
    float cf[8], af_[8];
#pragma unroll
    for (int i = 0; i < 8; i++) { cf[i] = bfs2f(cv[i]); af_[i] = bfs2f(av[i]); }
    unsigned char* rowp = cat8 + (long)j * FEAT + c;
    *(uint2*)(rowp) = pk8fp8(cf[0], cf[1], cf[2], cf[3], cf[4], cf[5], cf[6], cf[7]);
    *(uint2*)(rowp + 512) = pk8fp8(af_[0], af_[1], af_[2], af_[3], af_[4], af_[5], af_[6], af_[7]);
    *(uint2*)(rowp + 1024) = pk8fp8(af_[0] - cf[0], af_[1] - cf[1], af_[2] - cf[2], af_[3] - cf[3],
                                    af_[4] - cf[4], af_[5] - cf[5], af_[6] - cf[6], af_[7] - cf[7]);
    *(uint2*)(rowp + 1536) = pk8fp8(af_[0] * cf[0], af_[1] * cf[1], af_[2] * cf[2], af_[3] * cf[3],
                                    af_[4] * cf[4], af_[5] * cf[5], af_[6] * cf[6], af_[7] * cf[7]);
}

extern "C" void kernel_launch(void* const* d_in, const int* in_sizes, int n_in,
                              void* d_out, int out_size, void* d_ws, size_t ws_size,
                              hipStream_t stream) {
    (void)in_sizes; (void)n_in; (void)out_size; (void)ws_size;
    const float* C = (const float*)d_in[0];
    const float* Q = (const float*)d_in[1];
    const int* Cmask = (const int*)d_in[2];
    const int* Qmask = (const int*)d_in[3];
    const float* W1 = (const float*)d_in[4];
    const float* b1 = (const float*)d_in[5];
    const float* Wf = (const float*)d_in[6];
    const float* bfp = (const float*)d_in[7];
    const float* Wg = (const float*)d_in[8];
    const float* bgp = (const float*)d_in[9];
    float* out = (float*)d_out;

    // ---- workspace layout (bytes). cat8 overlaps the dead early temps
    // (W1b/Qb/Qt/C_/Q_/S are all last read before build_cat writes cat8).
    // idx/cnts/offs live in the free gap [92,798,976 .. 134,217,728) that no
    // other buffer maps to at any time. ----
    char* ws = (char*)d_ws;
    unsigned char* cat8 = (unsigned char*)(ws + 0);     //  67,108,864 (compacted rows)
    bf16* W1b  = (bf16*)(ws + 0);                       //     524,288
    bf16* Qb   = (bf16*)(ws + 524288);                  //   8,388,608
    bf16* Qt   = (bf16*)(ws + 8912896);                 //   8,388,608
    bf16* C_   = (bf16*)(ws + 17301504);                //  33,554,432
    bf16* Q_   = (bf16*)(ws + 50855936);                //   8,388,608
    bf16* S    = (bf16*)(ws + 59244544);                //  33,554,432 (dead before cat8 write)
    int*  idx  = (int*)(ws + 92798976);                 //     131,072
    int*  cnts = (int*)(ws + 92930048);                 //          64
    int*  offs = (int*)(ws + 92930112);                 //          68
    bf16* Cb   = (bf16*)(ws + 134217728);               //  33,554,432
    bf16* attn = (bf16*)(ws + 167772160);               //  33,554,432
    unsigned char* Wf8 = (unsigned char*)(ws + 201326592); // 4,194,304
    unsigned char* Wg8 = (unsigned char*)(ws + 205520896); // 4,194,304 (end ~209.7MB)

    // 0. row compaction from Cmask (deterministic scan)
    mask_count<<<BATCH, 256, 0, stream>>>(Cmask, cnts);
    mask_scan<<<1, 64, 0, stream>>>(cnts, offs);
    mask_compact<<<BATCH, 256, 0, stream>>>(Cmask, offs, idx);

    // 1. dtype conversions
    cvt_f32_bf16<<<256, 256, 0, stream>>>(W1, W1b, DIM * DIM);
    cvt_f32_fp8_w<<<4096, 256, 0, stream>>>(Wf, Wf8, FEAT * FEAT);
    cvt_f32_fp8_w<<<4096, 256, 0, stream>>>(Wg, Wg8, FEAT * FEAT);
    cvt_f32_bf16<<<16384, 256, 0, stream>>>(C, Cb, MC * DIM);
    cvt_f32_bf16<<<4096, 256, 0, stream>>>(Q, Qb, MQ * DIM);
    transpose_q<<<dim3(16, 16, 16), dim3(32, 8), 0, stream>>>(Q, Qt);

    // 2. C_ = lrelu(C @ W1^T + b1), Q_ = lrelu(Q @ W1^T + b1)  (bf16 out)
    gemm_bt<MODE_BIAS_LRELU><<<dim3(4, 256, 1), 256, 0, stream>>>(
        Cb, W1b, C_, b1, DIM, DIM, 0, 0, 0);
    gemm_bt<MODE_BIAS_LRELU><<<dim3(4, 64, 1), 256, 0, stream>>>(
        Qb, W1b, Q_, b1, DIM, DIM, 0, 0, 0);

    // 3. S[b] = C_[b] @ Q_[b]^T  (batched, bf16 logits)
    gemm_bt<MODE_PLAIN><<<dim3(4, 16, 16), 256, 0, stream>>>(
        C_, Q_, S, nullptr, LQ, DIM,
        (long)LC * DIM, (long)LQ * DIM, (long)LC * LQ);

    // 4. masked softmax over q (in place, wave per row)
    softmax_rows<<<MC / 4, 256, 0, stream>>>(S, Cmask, Qmask);

    // 5. attn[b] = S[b] @ Q[b]   (B-operand = Qt, batched)
    gemm_bt<MODE_PLAIN><<<dim3(4, 16, 16), 256, 0, stream>>>(
        S, Qt, attn, nullptr, DIM, LQ,
        (long)LC * LQ, (long)DIM * LQ, (long)LC * DIM);

    // 6. cat8 = compacted [C | attn | attn-C | attn*C] (fp8)
    build_cat<<<8192, 256, 0, stream>>>(Cb, attn, cat8, idx, offs);

    // 7. masked rows of out are exactly -1e30
    fill_masked<<<4096, 256, 0, stream>>>(out, Cmask);

    // 8. fused MX-fp8 dual GEMM on compacted rows + scatter epilogue (fp32 out)
    gemm_dual_fp8<<<dim3(16, 256, 1), 256, 0, stream>>>(
        cat8, Wf8, Wg8, out, bfp, bgp, idx, offs);
}

// Round 6
// 716.824 us; speedup vs baseline: 7.7458x; 1.0228x over previous
//
#include <hip/hip_runtime.h>
#include <hip/hip_bf16.h>
#include <math.h>

using bf16 = __hip_bfloat16;
typedef __attribute__((ext_vector_type(8))) short s16x8;
typedef __attribute__((ext_vector_type(4))) float f32x4;
typedef __attribute__((ext_vector_type(8))) int i32x8;
typedef __attribute__((ext_vector_type(4))) int i32x4;

#define NEG_INF_F (-1e30f)

// ---------- constants for this problem ----------
static constexpr int BATCH = 16;
static constexpr int LC = 2048;
static constexpr int LQ = 512;
static constexpr int DIM = 512;
static constexpr int FEAT = 2048;          // 4*DIM
static constexpr int MC = BATCH * LC;      // 32768
static constexpr int MQ = BATCH * LQ;      // 8192

__device__ __forceinline__ float bfs2f(short s) {
    union { float f; unsigned u; } x;
    x.u = ((unsigned)(unsigned short)s) << 16;
    return x.f;
}
__device__ __forceinline__ short f2bfs(float f) {
    bf16 h = __float2bfloat16(f);
    short s; __builtin_memcpy(&s, &h, 2);
    return s;
}
// OCP e4m3 byte -> float (decoder, epilogue only)
__device__ __forceinline__ float fp8_to_f(unsigned b) {
    const unsigned s = b >> 7, e = (b >> 3) & 15, m = b & 7;
    const int ee = e ? (int)e : 1;
    const int mm = e ? (int)(8 + m) : (int)m;
    union { unsigned u; float f; } sc; sc.u = (unsigned)(ee + 117) << 23; // 2^(ee-10)
    const float v = (float)mm * sc.f;
    return s ? -v : v;
}
// pack 8 floats -> 8 fp8 e4m3 bytes (saturating RNE via HW cvt)
__device__ __forceinline__ uint2 pk8fp8(float a0, float a1, float a2, float a3,
                                        float a4, float a5, float a6, float a7) {
    uint2 r;
    int w0 = __builtin_amdgcn_cvt_pk_fp8_f32(a0, a1, 0, false);
    w0 = __builtin_amdgcn_cvt_pk_fp8_f32(a2, a3, w0, true);
    int w1 = __builtin_amdgcn_cvt_pk_fp8_f32(a4, a5, 0, false);
    w1 = __builtin_amdgcn_cvt_pk_fp8_f32(a6, a7, w1, true);
    r.x = (unsigned)w0; r.y = (unsigned)w1;
    return r;
}

#define GLL(gp, lp) __builtin_amdgcn_global_load_lds( \
    (const __attribute__((address_space(1))) void*)(gp), \
    (__attribute__((address_space(3))) void*)(lp), 16, 0, 0)

// ---------- fp32 -> bf16 convert ----------
__global__ __launch_bounds__(256) void cvt_f32_bf16(const float* __restrict__ in,
                                                    bf16* __restrict__ out, int n) {
    int i = (blockIdx.x * 256 + threadIdx.x) * 4;
    if (i + 3 < n) {
        float4 v = *(const float4*)(in + i);
        ushort4 o;
        o.x = (unsigned short)f2bfs(v.x);
        o.y = (unsigned short)f2bfs(v.y);
        o.z = (unsigned short)f2bfs(v.z);
        o.w = (unsigned short)f2bfs(v.w);
        *(ushort4*)(out + i) = o;
    } else {
        for (int k = i; k < n; k++) out[k] = __float2bfloat16(in[k]);
    }
}

// ---------- fp32 -> fp8 e4m3 with x32 pre-scale (weights; MX scale 2^-5 compensates) ----------
__global__ __launch_bounds__(256) void cvt_f32_fp8_w(const float* __restrict__ in,
                                                     unsigned char* __restrict__ out, int n) {
    int i = (blockIdx.x * 256 + threadIdx.x) * 4;
    if (i >= n) return;
    float4 v = *(const float4*)(in + i);
    int w0 = __builtin_amdgcn_cvt_pk_fp8_f32(v.x * 32.f, v.y * 32.f, 0, false);
    w0 = __builtin_amdgcn_cvt_pk_fp8_f32(v.z * 32.f, v.w * 32.f, w0, true);
    *(int*)(out + i) = w0;
}

// ---------- per-batch transpose: Q (B,LQ,DIM) f32 -> Qt (B,DIM,LQ) bf16 ----------
__global__ __launch_bounds__(256) void transpose_q(const float* __restrict__ Q,
                                                   bf16* __restrict__ Qt) {
    __shared__ float t[32][33];
    const int b = blockIdx.z;
    const int q0 = blockIdx.x * 32, d0 = blockIdx.y * 32;
    const int tx = threadIdx.x, ty = threadIdx.y; // 32 x 8
    const float* Qb = Q + (long)b * LQ * DIM;
    bf16* Qtb = Qt + (long)b * DIM * LQ;
#pragma unroll
    for (int i = 0; i < 32; i += 8)
        t[ty + i][tx] = Qb[(long)(q0 + ty + i) * DIM + d0 + tx];
    __syncthreads();
#pragma unroll
    for (int i = 0; i < 32; i += 8)
        Qtb[(long)(d0 + ty + i) * LQ + q0 + tx] = __float2bfloat16(t[tx][ty + i]);
}

// ---------- mask compaction: idx[j] = original row of j-th unmasked row ----------
// 3 tiny deterministic kernels (no atomics): per-batch count -> serial scan of 16
// -> per-batch compaction with wave/LDS prefix scan. offs[16] = Mprime (total).
__global__ __launch_bounds__(256) void mask_count(const int* __restrict__ cm,
                                                  int* __restrict__ cnt) {
    const int b = blockIdx.x;
    const int* p = cm + b * LC;
    int s = 0;
    for (int i = threadIdx.x; i < LC; i += 256) s += p[i] ? 1 : 0;
#pragma unroll
    for (int o = 32; o > 0; o >>= 1) s += __shfl_down(s, o, 64);
    __shared__ int red[4];
    if ((threadIdx.x & 63) == 0) red[threadIdx.x >> 6] = s;
    __syncthreads();
    if (threadIdx.x == 0) cnt[b] = red[0] + red[1] + red[2] + red[3];
}
__global__ void mask_scan(const int* __restrict__ cnt, int* __restrict__ off) {
    if (threadIdx.x == 0) {
        int a = 0;
        for (int b = 0; b < BATCH; b++) { off[b] = a; a += cnt[b]; }
        off[BATCH] = a;   // Mprime
    }
}
__global__ __launch_bounds__(256) void mask_compact(const int* __restrict__ cm,
                                                    const int* __restrict__ off,
                                                    int* __restrict__ idx) {
    const int b = blockIdx.x;
    const int tid = threadIdx.x;
    const int lane = tid & 63, wv = tid >> 6;
    const int* p = cm + b * LC + tid * 8;
    int f[8], ls = 0;
#pragma unroll
    for (int i = 0; i < 8; i++) { f[i] = p[i] ? 1 : 0; ls += f[i]; }
    int inc = ls;   // inclusive wave scan of per-thread sums
#pragma unroll
    for (int o = 1; o < 64; o <<= 1) {
        int y = __shfl_up(inc, o, 64);
        if (lane >= o) inc += y;
    }
    __shared__ int wsum[4];
    if (lane == 63) wsum[wv] = inc;
    __syncthreads();
    int base = off[b];
    for (int w = 0; w < wv; w++) base += wsum[w];
    int ex = base + inc - ls;             // global exclusive prefix
    const int orig = b * LC + tid * 8;
    for (int i = 0; i < 8; i++)
        if (f[i]) idx[ex++] = orig + i;
}

// ---------- gather + cvt: compacted Cbc[j] = bf16(C[idx[j]]) ----------
__global__ __launch_bounds__(128) void gather_cvt_c(const float* __restrict__ C,
                                                    const int* __restrict__ idx,
                                                    const int* __restrict__ offs,
                                                    bf16* __restrict__ Cbc) {
    const int j = blockIdx.x;
    if (j >= offs[BATCH]) return;
    const int m = idx[j];
    const float4 v = ((const float4*)(C + (long)m * DIM))[threadIdx.x];
    ushort4 o;
    o.x = (unsigned short)f2bfs(v.x);
    o.y = (unsigned short)f2bfs(v.y);
    o.z = (unsigned short)f2bfs(v.z);
    o.w = (unsigned short)f2bfs(v.w);
    ((ushort4*)(Cbc + (long)j * DIM))[threadIdx.x] = o;
}

// ---------- fill masked output rows with exactly -1e30 ----------
__global__ __launch_bounds__(256) void fill_masked(float* __restrict__ out,
                                                   const int* __restrict__ cm) {
    const float4 v = make_float4(NEG_INF_F, NEG_INF_F, NEG_INF_F, NEG_INF_F);
    const long total = (long)MC * (FEAT / 4);           // float4 elements
    const long stride = (long)gridDim.x * 256;
    for (long p = (long)blockIdx.x * 256 + threadIdx.x; p < total; p += stride) {
        const int row = (int)(p >> 9);                  // FEAT/4 = 512 f4 per row
        if (cm[row] == 0) ((float4*)out)[p] = v;
    }
}

// ---------- generic bf16 MFMA GEMM: Out[M,N] = A[M,K] @ B[N,K]^T ----------
// cmode 0: normal batched (z strides).
// cmode 1: A/Out rows are globally compacted; limit = offs[BATCH]; blocks past exit.
// cmode 2: per-batch compacted rows [offs[z], offs[z+1]) in A/Out; B batched by
//          strideB. Stores guarded by row < rows_left (overflow would corrupt the
//          next batch's compacted rows). Loads in-bounds: offs[15]+2047 < MC.
enum { MODE_PLAIN = 0, MODE_BIAS_LRELU = 1 };

template <int MODE>
__global__ __launch_bounds__(256)
void gemm_bt(const bf16* __restrict__ A, const bf16* __restrict__ B,
             void* __restrict__ Out,
             const float* __restrict__ bias,
             int N, int K,
             long strideA, long strideB, long strideO,
             const int* __restrict__ offs, int cmode) {
    constexpr int BM = 128, BN = 128, BK = 32;
    __shared__ __align__(16) bf16 As[BM * BK];
    __shared__ __align__(16) bf16 Bs[BN * BK];

    const int z = blockIdx.z;
    const int bm0 = blockIdx.y * BM;
    long aBase, oBase;
    int rows_left;          // valid rows remaining at this block's first row
    if (cmode == 0) {
        aBase = (long)z * strideA; oBase = (long)z * strideO; rows_left = 1 << 30;
    } else if (cmode == 1) {
        aBase = 0; oBase = 0;
        rows_left = offs[BATCH] - bm0;
        if (rows_left <= 0) return;
    } else {
        const int o0 = offs[z], o1 = offs[z + 1];
        aBase = (long)o0 * K; oBase = (long)o0 * N;
        rows_left = (o1 - o0) - bm0;
        if (rows_left <= 0) return;
    }
    const bf16* Ab = A + aBase;
    const bf16* Bb = B + (long)z * strideB;

    const int tid = threadIdx.x;
    const int wave = tid >> 6, lane = tid & 63;
    const int wm = (wave >> 1) * 64, wn = (wave & 1) * 64;
    const int lrow = lane & 15, lq = lane >> 4;

    const int bn0 = blockIdx.x * BN;

    const int srow = tid >> 2;
    const int scol = (tid & 3) * 8;

    const bf16* ag = Ab + (long)(bm0 + srow) * K + scol;
    const bf16* bg = Bb + (long)(bn0 + srow) * K + scol;
    bf16* asl = &As[srow * BK + scol];   // byte offset = tid*16: contiguous in lane order
    bf16* bsl = &Bs[srow * BK + scol];
    const long skip64 = (long)64 * K;

    f32x4 acc[4][4];
#pragma unroll
    for (int i = 0; i < 4; i++)
#pragma unroll
        for (int j = 0; j < 4; j++) acc[i][j] = (f32x4){0.f, 0.f, 0.f, 0.f};

    for (int k0 = 0; k0 < K; k0 += BK) {
        GLL(ag, asl);
        GLL(ag + skip64, asl + 64 * BK);
        GLL(bg, bsl);
        GLL(bg + skip64, bsl + 64 * BK);
        ag += BK; bg += BK;
        __syncthreads();

        s16x8 af[4], bfv[4];
#pragma unroll
        for (int f = 0; f < 4; f++)
            af[f] = *(const s16x8*)&As[(wm + f * 16 + lrow) * BK + lq * 8];
#pragma unroll
        for (int f = 0; f < 4; f++)
            bfv[f] = *(const s16x8*)&Bs[(wn + f * 16 + lrow) * BK + lq * 8];

#pragma unroll
        for (int i = 0; i < 4; i++)
#pragma unroll
            for (int j = 0; j < 4; j++)
                acc[i][j] = __builtin_amdgcn_mfma_f32_16x16x32_bf16(af[i], bfv[j], acc[i][j], 0, 0, 0);
        __syncthreads();
    }

    // epilogue: C/D layout col=lane&15, row=(lane>>4)*4+reg  [m89/m91-verified]
#pragma unroll
    for (int i = 0; i < 4; i++) {
#pragma unroll
        for (int j = 0; j < 4; j++) {
            const int n = bn0 + wn + j * 16 + lrow;
            const float bn_bias = (MODE == MODE_PLAIN) ? 0.f : bias[n];
#pragma unroll
            for (int r = 0; r < 4; r++) {
                const int mloc = wm + i * 16 + lq * 4 + r;   // row within block
                if (mloc < rows_left) {
                    const long off = oBase + (long)(bm0 + mloc) * N + n;
                    float v = acc[i][j][r];
                    if (MODE == MODE_PLAIN) {
                        ((bf16*)Out)[off] = __float2bfloat16(v);
                    } else { // MODE_BIAS_LRELU
                        v += bn_bias;
                        v = v > 0.f ? v : 0.01f * v;
                        ((bf16*)Out)[off] = __float2bfloat16(v);
                    }
                }
            }
        }
    }
}

// ---------- fused dual GEMM, MX-fp8 K=128, COMPACTED rows ----------
// fuse = tanh(cat@Wf^T+bf), gate = sigm(cat@Wg^T+bg), out[idx[m]] = g*fuse+(1-g)*cat
// A8 = COMPACTED cat fp8. K-loop/staging/LDS byte-identical to the verified 433us
// round-0 kernel (single 48KB buffer, 2 blocks/CU; rounds 1-4: every pipelined
// variant spilled or lost occupancy). Win = work deletion (~50% rows masked).
// B = weights pre-scaled x32 fp8 (MX scale 2^-5, byte 122); A scale 2^0 (byte 127).
// LDS tiles: 16B chunks XOR-swizzled: chunk c of row m at pos c^(m&7).
__global__ __launch_bounds__(256, 2)
void gemm_dual_fp8(const unsigned char* __restrict__ A8,
                   const unsigned char* __restrict__ Bf8,
                   const unsigned char* __restrict__ Bg8,
                   float* __restrict__ Out,
                   const float* __restrict__ biasf, const float* __restrict__ biasg,
                   const int* __restrict__ idx,
                   const int* __restrict__ offs) {
    constexpr int BM = 128, BN = 128;
    constexpr int N = FEAT, K = FEAT;   // K in bytes per row (fp8)
    __shared__ __align__(16) char As[BM * 128];
    __shared__ __align__(16) char Bfs[BN * 128];
    __shared__ __align__(16) char Bgs[BN * 128];

    const int Mp = offs[BATCH];
    const int bm0 = blockIdx.y * BM;
    if (bm0 >= Mp) return;               // uniform early-exit: row block fully masked out
    const int bn0 = blockIdx.x * BN;

    const int tid = threadIdx.x;
    const int wave = tid >> 6, lane = tid & 63;
    const int wm = (wave >> 1) * 64, wn = (wave & 1) * 64;
    const int lrow = lane & 15, lq = lane >> 4;

    // ---- staging: thread t writes LDS chunk q=t+256r at byte q*16; that chunk
    // holds global row (r0+32r), k-bytes (p ^ (r0&7))*16 .. +16 ----
    const int p = tid & 7, r0 = tid >> 3;
    const int xo = (p ^ (r0 & 7)) * 16;
    const unsigned char* agp = A8 + (long)(bm0 + r0) * K + xo;
    const unsigned char* bfgp = Bf8 + (long)(bn0 + r0) * K + xo;
    const unsigned char* bggp = Bg8 + (long)(bn0 + r0) * K + xo;
    char* asl = As + tid * 16;
    char* bfl = Bfs + tid * 16;
    char* bgl = Bgs + tid * 16;
    const long rowskip = (long)32 * K;

    // ---- fragment ds_read offsets (loop-invariant): frag (row, kq=lq) halves h=0,1
    // stored at row*128 + ((lq*2+h)^(row&7))*16 ----
    int offA0[4], offA1[4], offB0[4], offB1[4];
#pragma unroll
    for (int f = 0; f < 4; f++) {
        const int ra = wm + f * 16 + lrow;
        offA0[f] = ra * 128 + (((lq * 2 + 0) ^ (ra & 7)) * 16);
        offA1[f] = ra * 128 + (((lq * 2 + 1) ^ (ra & 7)) * 16);
        const int rb = wn + f * 16 + lrow;
        offB0[f] = rb * 128 + (((lq * 2 + 0) ^ (rb & 7)) * 16);
        offB1[f] = rb * 128 + (((lq * 2 + 1) ^ (rb & 7)) * 16);
    }

    f32x4 accf[4][4], accg[4][4];
#pragma unroll
    for (int i = 0; i < 4; i++)
#pragma unroll
        for (int j = 0; j < 4; j++) {
            accf[i][j] = (f32x4){0.f, 0.f, 0.f, 0.f};
            accg[i][j] = (f32x4){0.f, 0.f, 0.f, 0.f};
        }

    for (int k0 = 0; k0 < K; k0 += 128) {
#pragma unroll
        for (int r = 0; r < 4; r++) {
            GLL(agp + (long)r * rowskip, asl + r * 4096);
            GLL(bfgp + (long)r * rowskip, bfl + r * 4096);
            GLL(bggp + (long)r * rowskip, bgl + r * 4096);
        }
        agp += 128; bfgp += 128; bggp += 128;
        __syncthreads();

        i32x8 af[4];
#pragma unroll
        for (int f = 0; f < 4; f++) {
            const i32x4 lo = *(const i32x4*)(As + offA0[f]);
            const i32x4 hi = *(const i32x4*)(As + offA1[f]);
            af[f][0] = lo[0]; af[f][1] = lo[1]; af[f][2] = lo[2]; af[f][3] = lo[3];
            af[f][4] = hi[0]; af[f][5] = hi[1]; af[f][6] = hi[2]; af[f][7] = hi[3];
        }
#pragma unroll
        for (int j = 0; j < 4; j++) {
            i32x8 bfj, bgj;
            {
                const i32x4 lo = *(const i32x4*)(Bfs + offB0[j]);
                const i32x4 hi = *(const i32x4*)(Bfs + offB1[j]);
                bfj[0] = lo[0]; bfj[1] = lo[1]; bfj[2] = lo[2]; bfj[3] = lo[3];
                bfj[4] = hi[0]; bfj[5] = hi[1]; bfj[6] = hi[2]; bfj[7] = hi[3];
            }
            {
                const i32x4 lo = *(const i32x4*)(Bgs + offB0[j]);
                const i32x4 hi = *(const i32x4*)(Bgs + offB1[j]);
                bgj[0] = lo[0]; bgj[1] = lo[1]; bgj[2] = lo[2]; bgj[3] = lo[3];
                bgj[4] = hi[0]; bgj[5] = hi[1]; bgj[6] = hi[2]; bgj[7] = hi[3];
            }
#pragma unroll
            for (int i = 0; i < 4; i++)
                accf[i][j] = __builtin_amdgcn_mfma_scale_f32_16x16x128_f8f6f4(
                    af[i], bfj, accf[i][j], 0, 0, 0, 127, 0, 122);
#pragma unroll
            for (int i = 0; i < 4; i++)
                accg[i][j] = __builtin_amdgcn_mfma_scale_f32_16x16x128_f8f6f4(
                    af[i], bgj, accg[i][j], 0, 0, 0, 127, 0, 122);
        }
        __syncthreads();
    }

    // epilogue: C/D layout col=lane&15, row=(lane>>4)*4+reg; scatter via idx
#pragma unroll
    for (int j = 0; j < 4; j++) {
        const int n = bn0 + wn + j * 16 + lrow;
        const float bfb = biasf[n];
        const float bgb = biasg[n];
#pragma unroll
        for (int i = 0; i < 4; i++) {
#pragma unroll
            for (int r = 0; r < 4; r++) {
                const int m = bm0 + wm + i * 16 + lq * 4 + r;
                if (m < Mp) {
                    const float vf = accf[i][j][r] + bfb;
                    const float vg = accg[i][j][r] + bgb;
                    const float e = __expf(2.0f * fabsf(vf));
                    const float th = copysignf(1.0f - 2.0f / (e + 1.0f), vf);
                    const float g = 1.0f / (1.0f + __expf(-vg));
                    const float c = fp8_to_f(A8[(long)m * N + n]);
                    Out[(long)idx[m] * N + n] = g * th + (1.0f - g) * c;
                }
            }
        }
    }
}

// ---------- masked row softmax over LQ=512, in place on COMPACTED bf16 S ----------
// wave-per-row on compacted rows (all Cmask=1 by construction); batch for Qmask
// comes from idx[row]>>11. shfl_xor reductions only — no LDS, no __syncthreads.
__global__ __launch_bounds__(256) void softmax_rows(bf16* __restrict__ S,
                                                    const int* __restrict__ idx,
                                                    const int* __restrict__ offs,
                                                    const int* __restrict__ Qmask) {
    const int row = blockIdx.x * 4 + (threadIdx.x >> 6);   // compacted row
    if (row >= offs[BATCH]) return;
    const int lane = threadIdx.x & 63;
    const int b = idx[row] >> 11;       // LC = 2048
    bf16* srow = S + (long)row * LQ;
    short* sp = (short*)srow + lane * 8;

    const int* qm = Qmask + b * LQ + lane * 8;
    const int4 m0 = *(const int4*)(qm);
    const int4 m1 = *(const int4*)(qm + 4);
    const int msk[8] = {m0.x, m0.y, m0.z, m0.w, m1.x, m1.y, m1.z, m1.w};
    const s16x8 sv = *(const s16x8*)sp;

    float v[8];
    float mx = -3e38f;
#pragma unroll
    for (int i = 0; i < 8; i++) {
        v[i] = msk[i] ? bfs2f(sv[i]) : -3e38f;
        mx = fmaxf(mx, v[i]);
    }
#pragma unroll
    for (int o = 32; o > 0; o >>= 1) mx = fmaxf(mx, __shfl_xor(mx, o, 64));

    float e[8];
    float s = 0.f;
#pragma unroll
    for (int i = 0; i < 8; i++) {
        e[i] = msk[i] ? __expf(v[i] - mx) : 0.f;
        s += e[i];
    }
#pragma unroll
    for (int o = 32; o > 0; o >>= 1) s += __shfl_xor(s, o, 64);

    s16x8 ov;
    if (!(s > 0.f)) {
        const short u = f2bfs(1.0f / 512.0f);
#pragma unroll
        for (int i = 0; i < 8; i++) ov[i] = u;
    } else {
        const float inv = 1.0f / s;
#pragma unroll
        for (int i = 0; i < 8; i++) ov[i] = f2bfs(e[i] * inv);
    }
    *(s16x8*)sp = ov;
}

// ---------- build COMPACTED cat = [C | attn | attn-C | attn*C] as fp8 e4m3 ----------
// all inputs already compacted; no gather.
__global__ __launch_bounds__(256) void build_cat(const bf16* __restrict__ Cbc,
                                                 const bf16* __restrict__ attnc,
                                                 unsigned char* __restrict__ cat8,
                                                 const int* __restrict__ offs) {
    const long t = (long)blockIdx.x * 256 + threadIdx.x;
    const int j = (int)(t >> 6);
    if (j >= offs[BATCH]) return;
    const int c = (int)(t & 63) << 3;
    const s16x8 cv = *(const s16x8*)((const short*)Cbc + (long)j * DIM + c);
    const s16x8 av = *(const s16x8*)((const short*)attnc + (long)j * DIM + c);
    float cf[8], af_[8];
#pragma unroll
    for (int i = 0; i < 8; i++) { cf[i] = bfs2f(cv[i]); af_[i] = bfs2f(av[i]); }
    unsigned char* rowp = cat8 + (long)j * FEAT + c;
    *(uint2*)(rowp) = pk8fp8(cf[0], cf[1], cf[2], cf[3], cf[4], cf[5], cf[6], cf[7]);
    *(uint2*)(rowp + 512) = pk8fp8(af_[0], af_[1], af_[2], af_[3], af_[4], af_[5], af_[6], af_[7]);
    *(uint2*)(rowp + 1024) = pk8fp8(af_[0] - cf[0], af_[1] - cf[1], af_[2] - cf[2], af_[3] - cf[3],
                                    af_[4] - cf[4], af_[5] - cf[5], af_[6] - cf[6], af_[7] - cf[7]);
    *(uint2*)(rowp + 1536) = pk8fp8(af_[0] * cf[0], af_[1] * cf[1], af_[2] * cf[2], af_[3] * cf[3],
                                    af_[4] * cf[4], af_[5] * cf[5], af_[6] * cf[6], af_[7] * cf[7]);
}

extern "C" void kernel_launch(void* const* d_in, const int* in_sizes, int n_in,
                              void* d_out, int out_size, void* d_ws, size_t ws_size,
                              hipStream_t stream) {
    (void)in_sizes; (void)n_in; (void)out_size; (void)ws_size;
    const float* C = (const float*)d_in[0];
    const float* Q = (const float*)d_in[1];
    const int* Cmask = (const int*)d_in[2];
    const int* Qmask = (const int*)d_in[3];
    const float* W1 = (const float*)d_in[4];
    const float* b1 = (const float*)d_in[5];
    const float* Wf = (const float*)d_in[6];
    const float* bfp = (const float*)d_in[7];
    const float* Wg = (const float*)d_in[8];
    const float* bgp = (const float*)d_in[9];
    float* out = (float*)d_out;

    // ---- workspace layout (bytes). All row-buffers downstream of C are COMPACTED
    // (capacity MC rows, valid rows 0..Mprime). cat8 overlaps the dead early temps
    // (W1b/Qb/Qt/C_c/Q_/Sc are all last read before build_cat writes cat8).
    // idx/cnts/offs live in the gap [92.8MB .. 134.2MB) nothing else maps. ----
    char* ws = (char*)d_ws;
    unsigned char* cat8 = (unsigned char*)(ws + 0);     //  67,108,864 (compacted)
    bf16* W1b  = (bf16*)(ws + 0);                       //     524,288
    bf16* Qb   = (bf16*)(ws + 524288);                  //   8,388,608
    bf16* Qt   = (bf16*)(ws + 8912896);                 //   8,388,608
    bf16* C_c  = (bf16*)(ws + 17301504);                //  33,554,432 (compacted)
    bf16* Q_   = (bf16*)(ws + 50855936);                //   8,388,608
    bf16* Sc   = (bf16*)(ws + 59244544);                //  33,554,432 (compacted; dead before cat8)
    int*  idx  = (int*)(ws + 92798976);                 //     131,072
    int*  cnts = (int*)(ws + 92930048);                 //          64
    int*  offs = (int*)(ws + 92930112);                 //          68
    bf16* Cbc  = (bf16*)(ws + 134217728);               //  33,554,432 (compacted)
    bf16* attnc= (bf16*)(ws + 167772160);               //  33,554,432 (compacted)
    unsigned char* Wf8 = (unsigned char*)(ws + 201326592); // 4,194,304
    unsigned char* Wg8 = (unsigned char*)(ws + 205520896); // 4,194,304 (end ~209.7MB)

    // 0. row compaction from Cmask (deterministic scan)
    mask_count<<<BATCH, 256, 0, stream>>>(Cmask, cnts);
    mask_scan<<<1, 64, 0, stream>>>(cnts, offs);
    mask_compact<<<BATCH, 256, 0, stream>>>(Cmask, offs, idx);

    // 1. dtype conversions (C gathered+compacted)
    cvt_f32_bf16<<<256, 256, 0, stream>>>(W1, W1b, DIM * DIM);
    cvt_f32_fp8_w<<<4096, 256, 0, stream>>>(Wf, Wf8, FEAT * FEAT);
    cvt_f32_fp8_w<<<4096, 256, 0, stream>>>(Wg, Wg8, FEAT * FEAT);
    gather_cvt_c<<<MC, 128, 0, stream>>>(C, idx, offs, Cbc);
    cvt_f32_bf16<<<4096, 256, 0, stream>>>(Q, Qb, MQ * DIM);
    transpose_q<<<dim3(16, 16, 16), dim3(32, 8), 0, stream>>>(Q, Qt);

    // 2. C_c = lrelu(Cbc @ W1^T + b1) on compacted rows (cmode 1);
    //    Q_ = lrelu(Q @ W1^T + b1) full (cmode 0)
    gemm_bt<MODE_BIAS_LRELU><<<dim3(4, 256, 1), 256, 0, stream>>>(
        Cbc, W1b, C_c, b1, DIM, DIM, 0, 0, 0, offs, 1);
    gemm_bt<MODE_BIAS_LRELU><<<dim3(4, 64, 1), 256, 0, stream>>>(
        Qb, W1b, Q_, b1, DIM, DIM, 0, 0, 0, nullptr, 0);

    // 3. Sc = C_c @ Q_[b]^T on per-batch compacted rows (cmode 2)
    gemm_bt<MODE_PLAIN><<<dim3(4, 16, 16), 256, 0, stream>>>(
        C_c, Q_, Sc, nullptr, LQ, DIM,
        0, (long)LQ * DIM, 0, offs, 2);

    // 4. masked softmax over q (in place, wave per compacted row)
    softmax_rows<<<MC / 4, 256, 0, stream>>>(Sc, idx, offs, Qmask);

    // 5. attnc = Sc @ Q[b] on per-batch compacted rows (cmode 2; B = Qt)
    gemm_bt<MODE_PLAIN><<<dim3(4, 16, 16), 256, 0, stream>>>(
        Sc, Qt, attnc, nullptr, DIM, LQ,
        0, (long)DIM * LQ, 0, offs, 2);

    // 6. cat8 = compacted [C | attn | attn-C | attn*C] (fp8)
    build_cat<<<8192, 256, 0, stream>>>(Cbc, attnc, cat8, offs);

    // 7. masked rows of out are exactly -1e30
    fill_masked<<<4096, 256, 0, stream>>>(out, Cmask);

    // 8. fused MX-fp8 dual GEMM on compacted rows + scatter epilogue (fp32 out)
    gemm_dual_fp8<<<dim3(16, 256, 1), 256, 0, stream>>>(
        cat8, Wf8, Wg8, out, bfp, bgp, idx, offs);
}